// Round 6
// baseline (910.289 us; speedup 1.0000x reference)
//
#include <hip/hip_runtime.h>

typedef unsigned short u16;
typedef unsigned int   u32;
typedef __attribute__((ext_vector_type(4))) float floatx4;
typedef __attribute__((ext_vector_type(8))) short shortx8;

#define BB 8192
#define SS 18
#define DD 512

// ---------- helpers ----------
__device__ __forceinline__ u16 f2bf(float f){            // RNE f32->bf16
  u32 u = __float_as_uint(f);
  return (u16)((u + 0x7FFFu + ((u >> 16) & 1u)) >> 16);
}
__device__ __forceinline__ float bf2f(u16 x){ return __uint_as_float(((u32)x)<<16); }

__device__ __forceinline__ shortx8 pack8v(floatx4 a, floatx4 b){
  shortx8 t;
  t[0]=(short)f2bf(a[0]); t[1]=(short)f2bf(a[1]); t[2]=(short)f2bf(a[2]); t[3]=(short)f2bf(a[3]);
  t[4]=(short)f2bf(b[0]); t[5]=(short)f2bf(b[1]); t[6]=(short)f2bf(b[2]); t[7]=(short)f2bf(b[3]);
  return t;
}

__device__ __forceinline__ void gload16(const void* g, void* l){
  __builtin_amdgcn_global_load_lds((const __attribute__((address_space(1))) void*)g,
                                   (__attribute__((address_space(3))) void*)l, 16, 0, 0);
}

// 256-thread staging of one [128][64] bf16 unit (swizzled image), CALLS per wave
template<int CALLS>
__device__ __forceinline__ void gstage(const char* src, size_t rowStrideB, int chunkByteOff,
                                       char* lds, int wid, int lane){
#pragma unroll
  for (int i=0;i<CALLS;++i){
    int base = (wid*CALLS + i)*1024;
    int off  = base + lane*16;
    int row  = off >> 7;
    int blk  = ((off >> 4) & 7) ^ (row & 7);
    gload16(src + (size_t)row*rowStrideB + chunkByteOff + blk*16, lds + base);
  }
}

// 512-thread staging of one [128][64] bf16 unit: 2 insts/thread
__device__ __forceinline__ void gstage8(const char* src, size_t rowStrideB, int chunkByteOff,
                                        char* lds, int wid, int lane){
#pragma unroll
  for (int i=0;i<2;++i){
    int base = (wid*2 + i)*1024;
    int off  = base + lane*16;
    int row  = off >> 7;
    int blk  = ((off >> 4) & 7) ^ (row & 7);
    gload16(src + (size_t)row*rowStrideB + chunkByteOff + blk*16, lds + base);
  }
}
// 512-thread staging of a [256][64] chunk (two units, contiguous 32KB in LDS)
__device__ __forceinline__ void stage256(const char* src, size_t rowStrideB, int chunkByteOff,
                                         char* lds, int wid, int lane){
  gstage8(src, rowStrideB, chunkByteOff, lds, wid, lane);
  gstage8(src + 128*rowStrideB, rowStrideB, chunkByteOff, lds + 16384, wid, lane);
}

__device__ __forceinline__ void lds_store4(char* buf, int row, int rowBytes, int khByte,
                                           int swzMask, const shortx8* v){
#pragma unroll
  for (int q=0;q<4;++q){
    int off = row*rowBytes + khByte + q*16;
    off ^= (row & swzMask) << 4;
    *(shortx8*)(buf + off) = v[q];
  }
}

__device__ __forceinline__ void stage_bf16(char* buf, const u16* gsrc, size_t srcRowBytes, int tid){
  int row = tid >> 1, kh = tid & 1;
  const char* p = (const char*)gsrc + (size_t)row*srcRowBytes + kh*64;
  shortx8 v[4];
#pragma unroll
  for (int q=0;q<4;++q) v[q] = *(const shortx8*)(p + q*16);
  lds_store4(buf, row, 128, kh*64, 7, v);
}

__device__ __forceinline__ shortx8 lds_frag(const char* buf, int row, int rowBytes, int kByte,
                                            int swzMask, int lane){
  int off = row*rowBytes + kByte + ((lane>>4)<<4);
  off ^= (row & swzMask) << 4;
  return *(const shortx8*)(buf + off);
}

template<int MF, int NF>
__device__ __forceinline__ void mma64(const char* As, const char* Bs, int wm, int wn, int lane,
                                      floatx4 acc[MF][NF]){
#pragma unroll
  for (int kk=0; kk<2; ++kk){
    shortx8 a[MF], b[NF];
#pragma unroll
    for (int i=0;i<MF;++i) a[i] = lds_frag(As, wm + i*16 + (lane&15), 128, kk*64, 7, lane);
#pragma unroll
    for (int j=0;j<NF;++j) b[j] = lds_frag(Bs, wn + j*16 + (lane&15), 128, kk*64, 7, lane);
#pragma unroll
    for (int i=0;i<MF;++i)
#pragma unroll
      for (int j=0;j<NF;++j)
        acc[i][j] = __builtin_amdgcn_mfma_f32_16x16x32_bf16(a[i], b[j], acc[i][j], 0, 0, 0);
  }
}

// main-loop body for the 256x256 kernels: per-kk frag load + MFMA (48 live frag regs)
__device__ __forceinline__ void mma_256tile(const char* Ab, const char* Bb, int wm, int wn,
                                            int lane, floatx4 acc[8][4]){
#pragma unroll
  for (int kk=0;kk<2;++kk){
    shortx8 a[8], b[4];
#pragma unroll
    for (int i=0;i<8;++i) a[i] = lds_frag(Ab, wm + i*16 + (lane&15), 128, kk*64, 7, lane);
#pragma unroll
    for (int j=0;j<4;++j) b[j] = lds_frag(Bb, wn + j*16 + (lane&15), 128, kk*64, 7, lane);
    __builtin_amdgcn_s_setprio(1);
#pragma unroll
    for (int i=0;i<8;++i)
#pragma unroll
      for (int j=0;j<4;++j)
        acc[i][j] = __builtin_amdgcn_mfma_f32_16x16x32_bf16(a[i], b[j], acc[i][j], 0, 0, 0);
    __builtin_amdgcn_s_setprio(0);
  }
}

// bijective XCD chunking (nwg % 8 == 0)
__device__ __forceinline__ int xcd_swz(int bid, int nwg){
  int q = nwg >> 3;
  return (bid & 7)*q + (bid >> 3);
}

// ---------- prep ----------
__global__ __launch_bounds__(256) void transpose_w2(const float* __restrict__ src,
                                                    u16* __restrict__ dst,
                                                    int sKstride, int kSrcOff, int Kuse,
                                                    int N, int Kpad, int kDstOff){
  __shared__ float tile[32][33];
  int s = blockIdx.z;
  int k0 = blockIdx.x*32, n0 = blockIdx.y*32;
  int tx = threadIdx.x & 31, ty = threadIdx.x >> 5;
#pragma unroll
  for (int r=0;r<4;++r){
    int k = k0 + ty*4 + r;
    float v = (k < Kuse) ? src[((size_t)s*sKstride + kSrcOff + k)*N + n0 + tx] : 0.f;
    tile[ty*4+r][tx] = v;
  }
  __syncthreads();
#pragma unroll
  for (int r=0;r<4;++r){
    int n = n0 + ty*4 + r;
    dst[((size_t)s*N + n)*Kpad + kDstOff + k0 + tx] = f2bf(tile[tx][ty*4+r]);
  }
}

// ---------- bn (unchanged): h2b + gsb side-write ----------
__global__ __launch_bounds__(256) void k_bn(const float* __restrict__ gs,
     const u16* __restrict__ w1t, const u16* __restrict__ w2t,
     const float* __restrict__ b1, const float* __restrict__ b2,
     u16* __restrict__ h2b, u16* __restrict__ gsb){
  __shared__ __align__(16) char SMB[40960];
  int tid = threadIdx.x, lane = tid & 63, wid = tid >> 6;
  int nb = xcd_swz(blockIdx.x, 1152);
  int m0 = (nb & 63)*128, s = nb >> 6;
  floatx4 acc[2][2] = {};
  const char*  Bsrc = (const char*)w1t + (size_t)s*32*1024;
  size_t rowIdx = ((size_t)(m0 + (tid>>1))*SS + s)*DD + (tid&1)*32;
  const float* Ags  = gs + rowIdx;
  u16*         Gsb  = gsb + rowIdx;
  floatx4 fr[8];
  gstage<1>(Bsrc, 1024, 0, SMB+32768, wid, lane);
#pragma unroll
  for (int q=0;q<8;++q) fr[q] = *(const floatx4*)(Ags + q*4);
  for (int c=0;c<8;++c){
    char* Asc = SMB + (c&1)*16384;
    char* Bsc = SMB + 32768 + (c&1)*4096;
    { shortx8 v[4];
#pragma unroll
      for (int q=0;q<4;++q) v[q] = pack8v(fr[2*q], fr[2*q+1]);
      u16* gp = Gsb + c*64;
#pragma unroll
      for (int q=0;q<4;++q) *(shortx8*)(gp + q*8) = v[q];
      lds_store4(Asc, tid>>1, 128, (tid&1)*64, 7, v); }
    __syncthreads();
    int cn = c+1;
    if (cn < 8){
      gstage<1>(Bsrc, 1024, cn*128, SMB + 32768 + (cn&1)*4096, wid, lane);
      const float* p = Ags + cn*64;
#pragma unroll
      for (int q=0;q<8;++q) fr[q] = *(const floatx4*)(p + q*4);
    }
    mma64<2,2>(Asc, Bsc, wid*32, 0, lane, acc);
  }
  __syncthreads();
  char* G1  = SMB;
  char* W2s = SMB + 8192;
#pragma unroll
  for (int i=0;i<2;++i)
#pragma unroll
   for (int j=0;j<2;++j){
    int col = j*16 + (lane&15);
    float bias = b1[s*32 + col];
#pragma unroll
    for (int r=0;r<4;++r){
      int row = wid*32 + i*16 + ((lane>>4)<<2) + r;
      float v = fmaxf(acc[i][j][r] + bias, 0.f);
      int off = (row*64 + col*2) ^ ((row&3)<<4);
      *(u16*)(G1 + off) = f2bf(v);
    }
  }
  if (tid < 32){
    const u16* p = w2t + (size_t)s*32*32 + tid*32;
#pragma unroll
    for (int q=0;q<4;++q){
      int off = (tid*64 + q*16) ^ ((tid&3)<<4);
      *(shortx8*)(W2s + off) = *(const shortx8*)(p + q*8);
    }
  }
  __syncthreads();
  floatx4 acc2[2][2] = {};
  {
    shortx8 a[2], b[2];
#pragma unroll
    for (int i=0;i<2;++i) a[i] = lds_frag(G1,  wid*32 + i*16 + (lane&15), 64, 0, 3, lane);
#pragma unroll
    for (int j=0;j<2;++j) b[j] = lds_frag(W2s, j*16 + (lane&15),          64, 0, 3, lane);
#pragma unroll
    for (int i=0;i<2;++i)
#pragma unroll
      for (int j=0;j<2;++j)
        acc2[i][j] = __builtin_amdgcn_mfma_f32_16x16x32_bf16(a[i], b[j], acc2[i][j], 0,0,0);
  }
#pragma unroll
  for (int i=0;i<2;++i)
#pragma unroll
   for (int j=0;j<2;++j){
    int col = j*16 + (lane&15);
    float bias = b2[s*32 + col];
#pragma unroll
    for (int r=0;r<4;++r){
      int row = wid*32 + i*16 + ((lane>>4)<<2) + r;
      h2b[((size_t)(m0+row)*SS + s)*32 + col] = f2bf(acc2[i][j][r] + bias);
    }
  }
}

// ---------- gm + age (unchanged) ----------
__global__ __launch_bounds__(256) void k_gm(const u16* __restrict__ h2b,
     const u16* __restrict__ w1t, const u16* __restrict__ w2t,
     const float* __restrict__ b1, const float* __restrict__ b2,
     const float* __restrict__ ta, const float* __restrict__ aw1, const float* __restrict__ ab1,
     const float* __restrict__ aw2, const float* __restrict__ ab2,
     u16* __restrict__ gfab){
  __shared__ __align__(16) char As[128*128];
  __shared__ __align__(16) char Bs[128*128];
  __shared__ __align__(16) char G1[128*256];
  int tid=threadIdx.x, lane=tid&63, w=tid>>6;
  int m0 = blockIdx.x*128;
  floatx4 acc[2][8] = {};
  for (int c=0;c<9;++c){
    __syncthreads();
    stage_bf16(As, h2b + (size_t)m0*576 + c*64, 1152, tid);
    stage_bf16(Bs, w1t + c*64,                 1152, tid);
    __syncthreads();
    mma64<2,8>(As, Bs, w*32, 0, lane, acc);
  }
#pragma unroll
  for (int i=0;i<2;++i)
#pragma unroll
   for (int j=0;j<8;++j){
    int col = j*16 + (lane&15);
    float bias = b1[col];
#pragma unroll
    for (int r=0;r<4;++r){
      int row = w*32 + i*16 + ((lane>>4)<<2) + r;
      float v = fmaxf(acc[i][j][r] + bias, 0.f);
      int off = (row*256 + col*2) ^ ((row&7)<<4);
      *(u16*)(G1 + off) = f2bf(v);
    }
  }
  floatx4 acc2[2][8] = {};
  for (int c2=0;c2<2;++c2){
    __syncthreads();
    stage_bf16(Bs, w2t + c2*64, 256, tid);
    __syncthreads();
#pragma unroll
    for (int kk=0;kk<2;++kk){
      shortx8 a[2], b[8];
#pragma unroll
      for (int i=0;i<2;++i){
        int row = w*32 + i*16 + (lane&15);
        int off = (row*256 + c2*128 + kk*64 + ((lane>>4)<<4)) ^ ((row&7)<<4);
        a[i] = *(const shortx8*)(G1 + off);
      }
#pragma unroll
      for (int j=0;j<8;++j) b[j] = lds_frag(Bs, j*16 + (lane&15), 128, kk*64, 7, lane);
#pragma unroll
      for (int i=0;i<2;++i)
#pragma unroll
        for (int j=0;j<8;++j)
          acc2[i][j] = __builtin_amdgcn_mfma_f32_16x16x32_bf16(a[i], b[j], acc2[i][j], 0,0,0);
    }
  }
#pragma unroll
  for (int i=0;i<2;++i)
#pragma unroll
   for (int j=0;j<8;++j){
    int col = j*16 + (lane&15);
    float bias = b2[col];
#pragma unroll
    for (int r=0;r<4;++r){
      int row = w*32 + i*16 + ((lane>>4)<<2) + r;
      gfab[(size_t)(m0+row)*192 + col] = f2bf(acc2[i][j][r] + bias);
    }
  }
  if (tid < 128){
    int bidx = m0 + tid;
    float t = ta[bidx];
    float a1[16];
#pragma unroll
    for (int j2=0;j2<16;++j2){ float v = t*aw1[j2] + ab1[j2]; a1[j2] = fmaxf(v, 0.f); }
#pragma unroll
    for (int m=0;m<16;++m){
      float v = ab2[m];
#pragma unroll
      for (int j2=0;j2<16;++j2) v += a1[j2]*aw2[j2*16+m];
      gfab[(size_t)bidx*192 + 128 + m] = f2bf(v);
    }
    shortx8 zz = {};
#pragma unroll
    for (int z=0;z<6;++z) *(shortx8*)(gfab + (size_t)bidx*192 + 144 + z*8) = zz;
  }
}

// ---------- fc1: 256x256 tile, 8 waves, counted-vmcnt dbuf ----------
__global__ __launch_bounds__(512) void k_fc1(const u16* __restrict__ gfab,
     const u16* __restrict__ gsb, const u16* __restrict__ w1t,
     const float* __restrict__ b1, u16* __restrict__ y1b){
  __shared__ __align__(16) char SMB[131072];  // A dbuf 2x32K @0, B dbuf 2x32K @65536
  int tid=threadIdx.x, lane=tid&63, wid=tid>>6;
  int nb = xcd_swz(blockIdx.x, 1152);
  int n1 = nb&1, m0 = ((nb>>1)&31)*256, s = nb>>6;
  int wm = (wid>>2)*128, wn = (wid&3)*64;
  floatx4 acc[8][4] = {};
  const char* A0 = (const char*)gfab + (size_t)m0*384;
  const char* A1 = (const char*)gsb + ((size_t)m0*SS + s)*1024;
  const char* Bb = (const char*)w1t + ((size_t)s*512 + n1*256)*1408;
#define C1_ISSA(t) do{ int _t=(t); char* _d = SMB + (_t&1)*32768; \
    if (_t<3) stage256(A0, 384, _t*128, _d, wid, lane); \
    else      stage256(A1, (size_t)SS*1024, _t*128-384, _d, wid, lane); }while(0)
#define C1_ISSB(t) stage256(Bb, 1408, (t)*128, SMB + 65536 + ((t)&1)*32768, wid, lane)
  C1_ISSA(0); C1_ISSB(0); C1_ISSA(1); C1_ISSB(1);
#pragma unroll 1
  for (int c=0;c<11;++c){
    if (c<10) asm volatile("s_waitcnt vmcnt(8)" ::: "memory");
    else      asm volatile("s_waitcnt vmcnt(0)" ::: "memory");
    __builtin_amdgcn_s_barrier();
    __builtin_amdgcn_sched_barrier(0);
    const char* Ab = SMB + (c&1)*32768;
    const char* Bbuf = SMB + 65536 + (c&1)*32768;
    mma_256tile(Ab, Bbuf, wm, wn, lane, acc);
    asm volatile("s_waitcnt lgkmcnt(0)" ::: "memory");
    __builtin_amdgcn_s_barrier();
    __builtin_amdgcn_sched_barrier(0);
    if (c+2<11){ C1_ISSA(c+2); C1_ISSB(c+2); }
  }
  __syncthreads();
  // epilogue: relu+bias -> SMB [256][512B bf16] swizzled, then coalesced stores
#pragma unroll
  for (int i=0;i<8;++i)
#pragma unroll
   for (int j=0;j<4;++j){
    int col = wn + j*16 + (lane&15);
    float bias = b1[(size_t)s*512 + n1*256 + col];
#pragma unroll
    for (int r=0;r<4;++r){
      int row = wm + i*16 + ((lane>>4)<<2) + r;
      float v = fmaxf(acc[i][j][r] + bias, 0.f);
      int off = (row*512 + col*2) ^ ((row&7)<<4);
      *(u16*)(SMB + off) = f2bf(v);
    }
  }
  __syncthreads();
  {
    int row = tid>>1, half = tid&1;
    u16* gp = y1b + ((size_t)(m0+row)*SS + s)*DD + n1*256 + half*128;
#pragma unroll
    for (int q=0;q<16;++q){
      int off = (row*512 + half*256 + q*16) ^ ((row&7)<<4);
      *(shortx8*)(gp + q*8) = *(const shortx8*)(SMB + off);
    }
  }
}

// ---------- fc2: 256x256 tile, 8 waves, counted-vmcnt dbuf; out = y1 @ w2 + b2 + gs ----------
__global__ __launch_bounds__(512) void k_fc2(const u16* __restrict__ y1b,
     const u16* __restrict__ gsb, const u16* __restrict__ w2t,
     const float* __restrict__ b2, float* __restrict__ out){
  __shared__ __align__(16) char SMB[131072];
  int tid=threadIdx.x, lane=tid&63, wid=tid>>6;
  int nb = xcd_swz(blockIdx.x, 1152);
  int n1 = nb&1, m0 = ((nb>>1)&31)*256, s = nb>>6;
  int wm = (wid>>2)*128, wn = (wid&3)*64;
  floatx4 acc[8][4] = {};
  const char* Ab0 = (const char*)y1b + ((size_t)m0*SS + s)*1024;
  const char* Bb  = (const char*)w2t + ((size_t)s*512 + n1*256)*1024;
#define C2_ISSA(t) stage256(Ab0, (size_t)SS*1024, (t)*128, SMB + ((t)&1)*32768, wid, lane)
#define C2_ISSB(t) stage256(Bb, 1024, (t)*128, SMB + 65536 + ((t)&1)*32768, wid, lane)
  C2_ISSA(0); C2_ISSB(0); C2_ISSA(1); C2_ISSB(1);
#pragma unroll 1
  for (int c=0;c<8;++c){
    if (c<7) asm volatile("s_waitcnt vmcnt(8)" ::: "memory");
    else     asm volatile("s_waitcnt vmcnt(0)" ::: "memory");
    __builtin_amdgcn_s_barrier();
    __builtin_amdgcn_sched_barrier(0);
    const char* Ab = SMB + (c&1)*32768;
    const char* Bbuf = SMB + 65536 + (c&1)*32768;
    mma_256tile(Ab, Bbuf, wm, wn, lane, acc);
    asm volatile("s_waitcnt lgkmcnt(0)" ::: "memory");
    __builtin_amdgcn_s_barrier();
    __builtin_amdgcn_sched_barrier(0);
    if (c+2<8){ C2_ISSA(c+2); C2_ISSB(c+2); }
  }
  // epilogue in two row-halves via fp32 LDS [128][1024B]
  float* SMF = (float*)SMB;
#pragma unroll 1
  for (int h=0;h<2;++h){
    __syncthreads();
    if ((wid>>2) == h){
#pragma unroll
      for (int i=0;i<8;++i)
#pragma unroll
       for (int j=0;j<4;++j){
        int col = wn + j*16 + (lane&15);
#pragma unroll
        for (int r=0;r<4;++r){
          int rl = i*16 + ((lane>>4)<<2) + r;
          int off = (rl*1024 + col*4) ^ ((rl&7)<<4);
          *(float*)((char*)SMF + off) = acc[i][j][r];
        }
      }
    }
    __syncthreads();
    {
      int rl = tid>>2, quarter = tid&3;
      int grow = m0 + h*128 + rl;
      size_t gidx = ((size_t)grow*SS + s)*DD + n1*256 + quarter*64;
      const float* bp = b2 + (size_t)s*512 + n1*256 + quarter*64;
      const u16*   gp = gsb + gidx;
#pragma unroll
      for (int q2=0;q2<8;++q2){
        shortx8 gv = *(const shortx8*)(gp + q2*8);
        int off0 = (rl*1024 + quarter*256 + q2*32)      ^ ((rl&7)<<4);
        int off1 = (rl*1024 + quarter*256 + q2*32 + 16) ^ ((rl&7)<<4);
        floatx4 v0 = *(const floatx4*)((char*)SMF + off0);
        floatx4 v1 = *(const floatx4*)((char*)SMF + off1);
        floatx4 b0 = *(const floatx4*)(bp + q2*8);
        floatx4 b1v= *(const floatx4*)(bp + q2*8 + 4);
        floatx4 g0, g1;
        g0[0]=bf2f((u16)gv[0]); g0[1]=bf2f((u16)gv[1]); g0[2]=bf2f((u16)gv[2]); g0[3]=bf2f((u16)gv[3]);
        g1[0]=bf2f((u16)gv[4]); g1[1]=bf2f((u16)gv[5]); g1[2]=bf2f((u16)gv[6]); g1[3]=bf2f((u16)gv[7]);
        *(floatx4*)(out + gidx + q2*8)     = v0 + b0 + g0;
        *(floatx4*)(out + gidx + q2*8 + 4) = v1 + b1v + g1;
      }
    }
  }
}

// ---------- launch ----------
extern "C" void kernel_launch(void* const* d_in, const int* in_sizes, int n_in,
                              void* d_out, int out_size, void* d_ws, size_t ws_size,
                              hipStream_t stream){
  (void)in_sizes; (void)n_in; (void)out_size; (void)ws_size;
  const float* gs   = (const float*)d_in[1];
  const float* ta   = (const float*)d_in[2];
  const float* bnw1 = (const float*)d_in[3];
  const float* bnb1 = (const float*)d_in[4];
  const float* bnw2 = (const float*)d_in[5];
  const float* bnb2 = (const float*)d_in[6];
  const float* gmw1 = (const float*)d_in[7];
  const float* gmb1 = (const float*)d_in[8];
  const float* gmw2 = (const float*)d_in[9];
  const float* gmb2 = (const float*)d_in[10];
  const float* aw1  = (const float*)d_in[11];
  const float* ab1  = (const float*)d_in[12];
  const float* aw2  = (const float*)d_in[13];
  const float* ab2  = (const float*)d_in[14];
  const float* fcw1 = (const float*)d_in[15];
  const float* fcb1 = (const float*)d_in[16];
  const float* fcw2 = (const float*)d_in[17];
  const float* fcb2 = (const float*)d_in[18];

  char* ws = (char*)d_ws;
  u16* fcW1t = (u16*)(ws + 0);                  // 12,976,128
  u16* fcW2t = (u16*)(ws + 12976128);           //  9,437,184
  u16* bnW1t = (u16*)(ws + 22413312);           //    589,824
  u16* bnW2t = (u16*)(ws + 23003136);           //     36,864
  u16* gmW1t = (u16*)(ws + 23040000);           //    147,456
  u16* gmW2t = (u16*)(ws + 23187456);           //     32,768
  u16* h2b   = (u16*)(ws + 23220224);           //  9,437,184
  u16* gfab  = (u16*)(ws + 32657408);           //  3,145,728 (B x 192)
  u16* y1b   = (u16*)(ws + 35803136);           // 150,994,944
  u16* gsb   = (u16*)(ws + 186798080);          // 150,994,944 (end 337,793,024)
  float* out = (float*)d_out;

  dim3 blk(256);
  transpose_w2<<<dim3(16,1,18),  blk, 0, stream>>>(bnw1, bnW1t, 512, 0, 512,  32, 512, 0);
  transpose_w2<<<dim3(1,1,18),   blk, 0, stream>>>(bnw2, bnW2t,  32, 0,  32,  32,  32, 0);
  transpose_w2<<<dim3(18,4,1),   blk, 0, stream>>>(gmw1, gmW1t, 576, 0, 576, 128, 576, 0);
  transpose_w2<<<dim3(4,4,1),    blk, 0, stream>>>(gmw2, gmW2t, 128, 0, 128, 128, 128, 0);
  transpose_w2<<<dim3(6,16,18),  blk, 0, stream>>>(fcw1, fcW1t, 656, 0,   144, 512, 704, 0);
  transpose_w2<<<dim3(16,16,18), blk, 0, stream>>>(fcw1, fcW1t, 656, 144, 512, 512, 704, 192);
  transpose_w2<<<dim3(16,16,18), blk, 0, stream>>>(fcw2, fcW2t, 512, 0, 512, 512, 512, 0);

  k_bn <<<dim3(1152), blk,      0, stream>>>(gs, bnW1t, bnW2t, bnb1, bnb2, h2b, gsb);
  k_gm <<<dim3(64),   blk,      0, stream>>>(h2b, gmW1t, gmW2t, gmb1, gmb2, ta, aw1, ab1, aw2, ab2, gfab);
  k_fc1<<<dim3(1152), dim3(512), 0, stream>>>(gfab, gsb, fcW1t, fcb1, y1b);
  k_fc2<<<dim3(1152), dim3(512), 0, stream>>>(y1b, gsb, fcW2t, fcb2, out);
}

// Round 7
// 907.577 us; speedup vs baseline: 1.0030x; 1.0030x over previous
//
#include <hip/hip_runtime.h>

typedef unsigned short u16;
typedef unsigned int   u32;
typedef __attribute__((ext_vector_type(4))) float floatx4;
typedef __attribute__((ext_vector_type(8))) short shortx8;

#define BB 8192
#define SS 18
#define DD 512

// ---------- helpers ----------
__device__ __forceinline__ u16 f2bf(float f){            // RNE f32->bf16
  u32 u = __float_as_uint(f);
  return (u16)((u + 0x7FFFu + ((u >> 16) & 1u)) >> 16);
}
__device__ __forceinline__ float bf2f(u16 x){ return __uint_as_float(((u32)x)<<16); }

__device__ __forceinline__ shortx8 pack8v(floatx4 a, floatx4 b){
  shortx8 t;
  t[0]=(short)f2bf(a[0]); t[1]=(short)f2bf(a[1]); t[2]=(short)f2bf(a[2]); t[3]=(short)f2bf(a[3]);
  t[4]=(short)f2bf(b[0]); t[5]=(short)f2bf(b[1]); t[6]=(short)f2bf(b[2]); t[7]=(short)f2bf(b[3]);
  return t;
}

__device__ __forceinline__ void gload16(const void* g, void* l){
  __builtin_amdgcn_global_load_lds((const __attribute__((address_space(1))) void*)g,
                                   (__attribute__((address_space(3))) void*)l, 16, 0, 0);
}

// 256-thread staging of one [128][64] bf16 unit (swizzled image), CALLS per wave
template<int CALLS>
__device__ __forceinline__ void gstage(const char* src, size_t rowStrideB, int chunkByteOff,
                                       char* lds, int wid, int lane){
#pragma unroll
  for (int i=0;i<CALLS;++i){
    int base = (wid*CALLS + i)*1024;
    int off  = base + lane*16;
    int row  = off >> 7;
    int blk  = ((off >> 4) & 7) ^ (row & 7);
    gload16(src + (size_t)row*rowStrideB + chunkByteOff + blk*16, lds + base);
  }
}

// 512-thread staging of one [128][64] bf16 unit: 2 insts/thread
__device__ __forceinline__ void gstage8(const char* src, size_t rowStrideB, int chunkByteOff,
                                        char* lds, int wid, int lane){
#pragma unroll
  for (int i=0;i<2;++i){
    int base = (wid*2 + i)*1024;
    int off  = base + lane*16;
    int row  = off >> 7;
    int blk  = ((off >> 4) & 7) ^ (row & 7);
    gload16(src + (size_t)row*rowStrideB + chunkByteOff + blk*16, lds + base);
  }
}
// 512-thread staging of a [256][64] chunk (two units, contiguous 32KB in LDS)
__device__ __forceinline__ void stage256(const char* src, size_t rowStrideB, int chunkByteOff,
                                         char* lds, int wid, int lane){
  gstage8(src, rowStrideB, chunkByteOff, lds, wid, lane);
  gstage8(src + 128*rowStrideB, rowStrideB, chunkByteOff, lds + 16384, wid, lane);
}

__device__ __forceinline__ void lds_store4(char* buf, int row, int rowBytes, int khByte,
                                           int swzMask, const shortx8* v){
#pragma unroll
  for (int q=0;q<4;++q){
    int off = row*rowBytes + khByte + q*16;
    off ^= (row & swzMask) << 4;
    *(shortx8*)(buf + off) = v[q];
  }
}

__device__ __forceinline__ void stage_bf16(char* buf, const u16* gsrc, size_t srcRowBytes, int tid){
  int row = tid >> 1, kh = tid & 1;
  const char* p = (const char*)gsrc + (size_t)row*srcRowBytes + kh*64;
  shortx8 v[4];
#pragma unroll
  for (int q=0;q<4;++q) v[q] = *(const shortx8*)(p + q*16);
  lds_store4(buf, row, 128, kh*64, 7, v);
}

__device__ __forceinline__ shortx8 lds_frag(const char* buf, int row, int rowBytes, int kByte,
                                            int swzMask, int lane){
  int off = row*rowBytes + kByte + ((lane>>4)<<4);
  off ^= (row & swzMask) << 4;
  return *(const shortx8*)(buf + off);
}

template<int MF, int NF>
__device__ __forceinline__ void mma64(const char* As, const char* Bs, int wm, int wn, int lane,
                                      floatx4 acc[MF][NF]){
#pragma unroll
  for (int kk=0; kk<2; ++kk){
    shortx8 a[MF], b[NF];
#pragma unroll
    for (int i=0;i<MF;++i) a[i] = lds_frag(As, wm + i*16 + (lane&15), 128, kk*64, 7, lane);
#pragma unroll
    for (int j=0;j<NF;++j) b[j] = lds_frag(Bs, wn + j*16 + (lane&15), 128, kk*64, 7, lane);
#pragma unroll
    for (int i=0;i<MF;++i)
#pragma unroll
      for (int j=0;j<NF;++j)
        acc[i][j] = __builtin_amdgcn_mfma_f32_16x16x32_bf16(a[i], b[j], acc[i][j], 0, 0, 0);
  }
}

// main-loop body for the 256x256 kernels: per-kk frag load + MFMA (48 live frag regs)
__device__ __forceinline__ void mma_256tile(const char* Ab, const char* Bb, int wm, int wn,
                                            int lane, floatx4 acc[8][4]){
#pragma unroll
  for (int kk=0;kk<2;++kk){
    shortx8 a[8], b[4];
#pragma unroll
    for (int i=0;i<8;++i) a[i] = lds_frag(Ab, wm + i*16 + (lane&15), 128, kk*64, 7, lane);
#pragma unroll
    for (int j=0;j<4;++j) b[j] = lds_frag(Bb, wn + j*16 + (lane&15), 128, kk*64, 7, lane);
    __builtin_amdgcn_s_setprio(1);
#pragma unroll
    for (int i=0;i<8;++i)
#pragma unroll
      for (int j=0;j<4;++j)
        acc[i][j] = __builtin_amdgcn_mfma_f32_16x16x32_bf16(a[i], b[j], acc[i][j], 0, 0, 0);
    __builtin_amdgcn_s_setprio(0);
  }
}

// bijective XCD chunking (nwg % 8 == 0)
__device__ __forceinline__ int xcd_swz(int bid, int nwg){
  int q = nwg >> 3;
  return (bid & 7)*q + (bid >> 3);
}

// ---------- prep ----------
__global__ __launch_bounds__(256) void transpose_w2(const float* __restrict__ src,
                                                    u16* __restrict__ dst,
                                                    int sKstride, int kSrcOff, int Kuse,
                                                    int N, int Kpad, int kDstOff){
  __shared__ float tile[32][33];
  int s = blockIdx.z;
  int k0 = blockIdx.x*32, n0 = blockIdx.y*32;
  int tx = threadIdx.x & 31, ty = threadIdx.x >> 5;
#pragma unroll
  for (int r=0;r<4;++r){
    int k = k0 + ty*4 + r;
    float v = (k < Kuse) ? src[((size_t)s*sKstride + kSrcOff + k)*N + n0 + tx] : 0.f;
    tile[ty*4+r][tx] = v;
  }
  __syncthreads();
#pragma unroll
  for (int r=0;r<4;++r){
    int n = n0 + ty*4 + r;
    dst[((size_t)s*N + n)*Kpad + kDstOff + k0 + tx] = f2bf(tile[tx][ty*4+r]);
  }
}

// ---------- bn (unchanged): h2b + gsb side-write ----------
__global__ __launch_bounds__(256) void k_bn(const float* __restrict__ gs,
     const u16* __restrict__ w1t, const u16* __restrict__ w2t,
     const float* __restrict__ b1, const float* __restrict__ b2,
     u16* __restrict__ h2b, u16* __restrict__ gsb){
  __shared__ __align__(16) char SMB[40960];
  int tid = threadIdx.x, lane = tid & 63, wid = tid >> 6;
  int nb = xcd_swz(blockIdx.x, 1152);
  int m0 = (nb & 63)*128, s = nb >> 6;
  floatx4 acc[2][2] = {};
  const char*  Bsrc = (const char*)w1t + (size_t)s*32*1024;
  size_t rowIdx = ((size_t)(m0 + (tid>>1))*SS + s)*DD + (tid&1)*32;
  const float* Ags  = gs + rowIdx;
  u16*         Gsb  = gsb + rowIdx;
  floatx4 fr[8];
  gstage<1>(Bsrc, 1024, 0, SMB+32768, wid, lane);
#pragma unroll
  for (int q=0;q<8;++q) fr[q] = *(const floatx4*)(Ags + q*4);
  for (int c=0;c<8;++c){
    char* Asc = SMB + (c&1)*16384;
    char* Bsc = SMB + 32768 + (c&1)*4096;
    { shortx8 v[4];
#pragma unroll
      for (int q=0;q<4;++q) v[q] = pack8v(fr[2*q], fr[2*q+1]);
      u16* gp = Gsb + c*64;
#pragma unroll
      for (int q=0;q<4;++q) *(shortx8*)(gp + q*8) = v[q];
      lds_store4(Asc, tid>>1, 128, (tid&1)*64, 7, v); }
    __syncthreads();
    int cn = c+1;
    if (cn < 8){
      gstage<1>(Bsrc, 1024, cn*128, SMB + 32768 + (cn&1)*4096, wid, lane);
      const float* p = Ags + cn*64;
#pragma unroll
      for (int q=0;q<8;++q) fr[q] = *(const floatx4*)(p + q*4);
    }
    mma64<2,2>(Asc, Bsc, wid*32, 0, lane, acc);
  }
  __syncthreads();
  char* G1  = SMB;
  char* W2s = SMB + 8192;
#pragma unroll
  for (int i=0;i<2;++i)
#pragma unroll
   for (int j=0;j<2;++j){
    int col = j*16 + (lane&15);
    float bias = b1[s*32 + col];
#pragma unroll
    for (int r=0;r<4;++r){
      int row = wid*32 + i*16 + ((lane>>4)<<2) + r;
      float v = fmaxf(acc[i][j][r] + bias, 0.f);
      int off = (row*64 + col*2) ^ ((row&3)<<4);
      *(u16*)(G1 + off) = f2bf(v);
    }
  }
  if (tid < 32){
    const u16* p = w2t + (size_t)s*32*32 + tid*32;
#pragma unroll
    for (int q=0;q<4;++q){
      int off = (tid*64 + q*16) ^ ((tid&3)<<4);
      *(shortx8*)(W2s + off) = *(const shortx8*)(p + q*8);
    }
  }
  __syncthreads();
  floatx4 acc2[2][2] = {};
  {
    shortx8 a[2], b[2];
#pragma unroll
    for (int i=0;i<2;++i) a[i] = lds_frag(G1,  wid*32 + i*16 + (lane&15), 64, 0, 3, lane);
#pragma unroll
    for (int j=0;j<2;++j) b[j] = lds_frag(W2s, j*16 + (lane&15),          64, 0, 3, lane);
#pragma unroll
    for (int i=0;i<2;++i)
#pragma unroll
      for (int j=0;j<2;++j)
        acc2[i][j] = __builtin_amdgcn_mfma_f32_16x16x32_bf16(a[i], b[j], acc2[i][j], 0,0,0);
  }
#pragma unroll
  for (int i=0;i<2;++i)
#pragma unroll
   for (int j=0;j<2;++j){
    int col = j*16 + (lane&15);
    float bias = b2[s*32 + col];
#pragma unroll
    for (int r=0;r<4;++r){
      int row = wid*32 + i*16 + ((lane>>4)<<2) + r;
      h2b[((size_t)(m0+row)*SS + s)*32 + col] = f2bf(acc2[i][j][r] + bias);
    }
  }
}

// ---------- gm + age (unchanged) ----------
__global__ __launch_bounds__(256) void k_gm(const u16* __restrict__ h2b,
     const u16* __restrict__ w1t, const u16* __restrict__ w2t,
     const float* __restrict__ b1, const float* __restrict__ b2,
     const float* __restrict__ ta, const float* __restrict__ aw1, const float* __restrict__ ab1,
     const float* __restrict__ aw2, const float* __restrict__ ab2,
     u16* __restrict__ gfab){
  __shared__ __align__(16) char As[128*128];
  __shared__ __align__(16) char Bs[128*128];
  __shared__ __align__(16) char G1[128*256];
  int tid=threadIdx.x, lane=tid&63, w=tid>>6;
  int m0 = blockIdx.x*128;
  floatx4 acc[2][8] = {};
  for (int c=0;c<9;++c){
    __syncthreads();
    stage_bf16(As, h2b + (size_t)m0*576 + c*64, 1152, tid);
    stage_bf16(Bs, w1t + c*64,                 1152, tid);
    __syncthreads();
    mma64<2,8>(As, Bs, w*32, 0, lane, acc);
  }
#pragma unroll
  for (int i=0;i<2;++i)
#pragma unroll
   for (int j=0;j<8;++j){
    int col = j*16 + (lane&15);
    float bias = b1[col];
#pragma unroll
    for (int r=0;r<4;++r){
      int row = w*32 + i*16 + ((lane>>4)<<2) + r;
      float v = fmaxf(acc[i][j][r] + bias, 0.f);
      int off = (row*256 + col*2) ^ ((row&7)<<4);
      *(u16*)(G1 + off) = f2bf(v);
    }
  }
  floatx4 acc2[2][8] = {};
  for (int c2=0;c2<2;++c2){
    __syncthreads();
    stage_bf16(Bs, w2t + c2*64, 256, tid);
    __syncthreads();
#pragma unroll
    for (int kk=0;kk<2;++kk){
      shortx8 a[2], b[8];
#pragma unroll
      for (int i=0;i<2;++i){
        int row = w*32 + i*16 + (lane&15);
        int off = (row*256 + c2*128 + kk*64 + ((lane>>4)<<4)) ^ ((row&7)<<4);
        a[i] = *(const shortx8*)(G1 + off);
      }
#pragma unroll
      for (int j=0;j<8;++j) b[j] = lds_frag(Bs, j*16 + (lane&15), 128, kk*64, 7, lane);
#pragma unroll
      for (int i=0;i<2;++i)
#pragma unroll
        for (int j=0;j<8;++j)
          acc2[i][j] = __builtin_amdgcn_mfma_f32_16x16x32_bf16(a[i], b[j], acc2[i][j], 0,0,0);
    }
  }
#pragma unroll
  for (int i=0;i<2;++i)
#pragma unroll
   for (int j=0;j<8;++j){
    int col = j*16 + (lane&15);
    float bias = b2[col];
#pragma unroll
    for (int r=0;r<4;++r){
      int row = w*32 + i*16 + ((lane>>4)<<2) + r;
      gfab[(size_t)(m0+row)*192 + col] = f2bf(acc2[i][j][r] + bias);
    }
  }
  if (tid < 128){
    int bidx = m0 + tid;
    float t = ta[bidx];
    float a1[16];
#pragma unroll
    for (int j2=0;j2<16;++j2){ float v = t*aw1[j2] + ab1[j2]; a1[j2] = fmaxf(v, 0.f); }
#pragma unroll
    for (int m=0;m<16;++m){
      float v = ab2[m];
#pragma unroll
      for (int j2=0;j2<16;++j2) v += a1[j2]*aw2[j2*16+m];
      gfab[(size_t)bidx*192 + 128 + m] = f2bf(v);
    }
    shortx8 zz = {};
#pragma unroll
    for (int z=0;z<6;++z) *(shortx8*)(gfab + (size_t)bidx*192 + 144 + z*8) = zz;
  }
}

// ---------- fc1: 256x256 tile, 8 waves, counted-vmcnt dbuf ----------
__global__ __launch_bounds__(512, 2) void k_fc1(const u16* __restrict__ gfab,
     const u16* __restrict__ gsb, const u16* __restrict__ w1t,
     const float* __restrict__ b1, u16* __restrict__ y1b){
  __shared__ __align__(16) char SMB[131072];  // A dbuf 2x32K @0, B dbuf 2x32K @65536
  int tid=threadIdx.x, lane=tid&63, wid=tid>>6;
  int nb = xcd_swz(blockIdx.x, 1152);
  int n1 = nb&1, m0 = ((nb>>1)&31)*256, s = nb>>6;
  int wm = (wid>>2)*128, wn = (wid&3)*64;
  floatx4 acc[8][4] = {};
  const char* A0 = (const char*)gfab + (size_t)m0*384;
  const char* A1 = (const char*)gsb + ((size_t)m0*SS + s)*1024;
  const char* Bb = (const char*)w1t + ((size_t)s*512 + n1*256)*1408;
#define C1_ISSA(t) do{ int _t=(t); char* _d = SMB + (_t&1)*32768; \
    if (_t<3) stage256(A0, 384, _t*128, _d, wid, lane); \
    else      stage256(A1, (size_t)SS*1024, _t*128-384, _d, wid, lane); }while(0)
#define C1_ISSB(t) stage256(Bb, 1408, (t)*128, SMB + 65536 + ((t)&1)*32768, wid, lane)
  C1_ISSA(0); C1_ISSB(0); C1_ISSA(1); C1_ISSB(1);
#pragma unroll 1
  for (int c=0;c<11;++c){
    if (c<10) asm volatile("s_waitcnt vmcnt(8)" ::: "memory");
    else      asm volatile("s_waitcnt vmcnt(0)" ::: "memory");
    __builtin_amdgcn_s_barrier();
    __builtin_amdgcn_sched_barrier(0);
    const char* Ab = SMB + (c&1)*32768;
    const char* Bbuf = SMB + 65536 + (c&1)*32768;
    mma_256tile(Ab, Bbuf, wm, wn, lane, acc);
    asm volatile("s_waitcnt lgkmcnt(0)" ::: "memory");
    __builtin_amdgcn_s_barrier();
    __builtin_amdgcn_sched_barrier(0);
    if (c+2<11){ C1_ISSA(c+2); C1_ISSB(c+2); }
  }
  __syncthreads();
  // epilogue: relu+bias -> SMB [256][512B bf16] swizzled, then coalesced stores
#pragma unroll
  for (int i=0;i<8;++i)
#pragma unroll
   for (int j=0;j<4;++j){
    int col = wn + j*16 + (lane&15);
    float bias = b1[(size_t)s*512 + n1*256 + col];
#pragma unroll
    for (int r=0;r<4;++r){
      int row = wm + i*16 + ((lane>>4)<<2) + r;
      float v = fmaxf(acc[i][j][r] + bias, 0.f);
      int off = (row*512 + col*2) ^ ((row&7)<<4);
      *(u16*)(SMB + off) = f2bf(v);
    }
  }
  __syncthreads();
  {
    int row = tid>>1, half = tid&1;
    u16* gp = y1b + ((size_t)(m0+row)*SS + s)*DD + n1*256 + half*128;
#pragma unroll
    for (int q=0;q<16;++q){
      int off = (row*512 + half*256 + q*16) ^ ((row&7)<<4);
      *(shortx8*)(gp + q*8) = *(const shortx8*)(SMB + off);
    }
  }
}

// ---------- fc2: 256x256 tile, 8 waves, counted-vmcnt dbuf; out = y1 @ w2 + b2 + gs ----------
__global__ __launch_bounds__(512, 2) void k_fc2(const u16* __restrict__ y1b,
     const u16* __restrict__ gsb, const u16* __restrict__ w2t,
     const float* __restrict__ b2, float* __restrict__ out){
  __shared__ __align__(16) char SMB[131072];
  int tid=threadIdx.x, lane=tid&63, wid=tid>>6;
  int nb = xcd_swz(blockIdx.x, 1152);
  int n1 = nb&1, m0 = ((nb>>1)&31)*256, s = nb>>6;
  int wm = (wid>>2)*128, wn = (wid&3)*64;
  floatx4 acc[8][4] = {};
  const char* Ab0 = (const char*)y1b + ((size_t)m0*SS + s)*1024;
  const char* Bb  = (const char*)w2t + ((size_t)s*512 + n1*256)*1024;
#define C2_ISSA(t) stage256(Ab0, (size_t)SS*1024, (t)*128, SMB + ((t)&1)*32768, wid, lane)
#define C2_ISSB(t) stage256(Bb, 1024, (t)*128, SMB + 65536 + ((t)&1)*32768, wid, lane)
  C2_ISSA(0); C2_ISSB(0); C2_ISSA(1); C2_ISSB(1);
#pragma unroll 1
  for (int c=0;c<8;++c){
    if (c<7) asm volatile("s_waitcnt vmcnt(8)" ::: "memory");
    else     asm volatile("s_waitcnt vmcnt(0)" ::: "memory");
    __builtin_amdgcn_s_barrier();
    __builtin_amdgcn_sched_barrier(0);
    const char* Ab = SMB + (c&1)*32768;
    const char* Bbuf = SMB + 65536 + (c&1)*32768;
    mma_256tile(Ab, Bbuf, wm, wn, lane, acc);
    asm volatile("s_waitcnt lgkmcnt(0)" ::: "memory");
    __builtin_amdgcn_s_barrier();
    __builtin_amdgcn_sched_barrier(0);
    if (c+2<8){ C2_ISSA(c+2); C2_ISSB(c+2); }
  }
  // epilogue in two row-halves via fp32 LDS [128][1024B]
  float* SMF = (float*)SMB;
#pragma unroll 1
  for (int h=0;h<2;++h){
    __syncthreads();
    if ((wid>>2) == h){
#pragma unroll
      for (int i=0;i<8;++i)
#pragma unroll
       for (int j=0;j<4;++j){
        int col = wn + j*16 + (lane&15);
#pragma unroll
        for (int r=0;r<4;++r){
          int rl = i*16 + ((lane>>4)<<2) + r;
          int off = (rl*1024 + col*4) ^ ((rl&7)<<4);
          *(float*)((char*)SMF + off) = acc[i][j][r];
        }
      }
    }
    __syncthreads();
    {
      int rl = tid>>2, quarter = tid&3;
      int grow = m0 + h*128 + rl;
      size_t gidx = ((size_t)grow*SS + s)*DD + n1*256 + quarter*64;
      const float* bp = b2 + (size_t)s*512 + n1*256 + quarter*64;
      const u16*   gp = gsb + gidx;
#pragma unroll
      for (int q2=0;q2<8;++q2){
        shortx8 gv = *(const shortx8*)(gp + q2*8);
        int off0 = (rl*1024 + quarter*256 + q2*32)      ^ ((rl&7)<<4);
        int off1 = (rl*1024 + quarter*256 + q2*32 + 16) ^ ((rl&7)<<4);
        floatx4 v0 = *(const floatx4*)((char*)SMF + off0);
        floatx4 v1 = *(const floatx4*)((char*)SMF + off1);
        floatx4 b0 = *(const floatx4*)(bp + q2*8);
        floatx4 b1v= *(const floatx4*)(bp + q2*8 + 4);
        floatx4 g0, g1;
        g0[0]=bf2f((u16)gv[0]); g0[1]=bf2f((u16)gv[1]); g0[2]=bf2f((u16)gv[2]); g0[3]=bf2f((u16)gv[3]);
        g1[0]=bf2f((u16)gv[4]); g1[1]=bf2f((u16)gv[5]); g1[2]=bf2f((u16)gv[6]); g1[3]=bf2f((u16)gv[7]);
        *(floatx4*)(out + gidx + q2*8)     = v0 + b0 + g0;
        *(floatx4*)(out + gidx + q2*8 + 4) = v1 + b1v + g1;
      }
    }
  }
}

// ---------- launch ----------
extern "C" void kernel_launch(void* const* d_in, const int* in_sizes, int n_in,
                              void* d_out, int out_size, void* d_ws, size_t ws_size,
                              hipStream_t stream){
  (void)in_sizes; (void)n_in; (void)out_size; (void)ws_size;
  const float* gs   = (const float*)d_in[1];
  const float* ta   = (const float*)d_in[2];
  const float* bnw1 = (const float*)d_in[3];
  const float* bnb1 = (const float*)d_in[4];
  const float* bnw2 = (const float*)d_in[5];
  const float* bnb2 = (const float*)d_in[6];
  const float* gmw1 = (const float*)d_in[7];
  const float* gmb1 = (const float*)d_in[8];
  const float* gmw2 = (const float*)d_in[9];
  const float* gmb2 = (const float*)d_in[10];
  const float* aw1  = (const float*)d_in[11];
  const float* ab1  = (const float*)d_in[12];
  const float* aw2  = (const float*)d_in[13];
  const float* ab2  = (const float*)d_in[14];
  const float* fcw1 = (const float*)d_in[15];
  const float* fcb1 = (const float*)d_in[16];
  const float* fcw2 = (const float*)d_in[17];
  const float* fcb2 = (const float*)d_in[18];

  char* ws = (char*)d_ws;
  u16* fcW1t = (u16*)(ws + 0);                  // 12,976,128
  u16* fcW2t = (u16*)(ws + 12976128);           //  9,437,184
  u16* bnW1t = (u16*)(ws + 22413312);           //    589,824
  u16* bnW2t = (u16*)(ws + 23003136);           //     36,864
  u16* gmW1t = (u16*)(ws + 23040000);           //    147,456
  u16* gmW2t = (u16*)(ws + 23187456);           //     32,768
  u16* h2b   = (u16*)(ws + 23220224);           //  9,437,184
  u16* gfab  = (u16*)(ws + 32657408);           //  3,145,728 (B x 192)
  u16* y1b   = (u16*)(ws + 35803136);           // 150,994,944
  u16* gsb   = (u16*)(ws + 186798080);          // 150,994,944 (end 337,793,024)
  float* out = (float*)d_out;

  dim3 blk(256);
  transpose_w2<<<dim3(16,1,18),  blk, 0, stream>>>(bnw1, bnW1t, 512, 0, 512,  32, 512, 0);
  transpose_w2<<<dim3(1,1,18),   blk, 0, stream>>>(bnw2, bnW2t,  32, 0,  32,  32,  32, 0);
  transpose_w2<<<dim3(18,4,1),   blk, 0, stream>>>(gmw1, gmW1t, 576, 0, 576, 128, 576, 0);
  transpose_w2<<<dim3(4,4,1),    blk, 0, stream>>>(gmw2, gmW2t, 128, 0, 128, 128, 128, 0);
  transpose_w2<<<dim3(6,16,18),  blk, 0, stream>>>(fcw1, fcW1t, 656, 0,   144, 512, 704, 0);
  transpose_w2<<<dim3(16,16,18), blk, 0, stream>>>(fcw1, fcW1t, 656, 144, 512, 512, 704, 192);
  transpose_w2<<<dim3(16,16,18), blk, 0, stream>>>(fcw2, fcW2t, 512, 0, 512, 512, 512, 0);

  k_bn <<<dim3(1152), blk,      0, stream>>>(gs, bnW1t, bnW2t, bnb1, bnb2, h2b, gsb);
  k_gm <<<dim3(64),   blk,      0, stream>>>(h2b, gmW1t, gmW2t, gmb1, gmb2, ta, aw1, ab1, aw2, ab2, gfab);
  k_fc1<<<dim3(1152), dim3(512), 0, stream>>>(gfab, gsb, fcW1t, fcb1, y1b);
  k_fc2<<<dim3(1152), dim3(512), 0, stream>>>(y1b, gsb, fcW2t, fcb2, out);
}

// Round 8
// 896.207 us; speedup vs baseline: 1.0157x; 1.0127x over previous
//
#include <hip/hip_runtime.h>

typedef unsigned short u16;
typedef unsigned int   u32;
typedef __attribute__((ext_vector_type(4))) float floatx4;
typedef __attribute__((ext_vector_type(8))) short shortx8;

#define BB 8192
#define SS 18
#define DD 512

// ---------- helpers ----------
__device__ __forceinline__ u16 f2bf(float f){            // RNE f32->bf16
  u32 u = __float_as_uint(f);
  return (u16)((u + 0x7FFFu + ((u >> 16) & 1u)) >> 16);
}
__device__ __forceinline__ float bf2f(u16 x){ return __uint_as_float(((u32)x)<<16); }

__device__ __forceinline__ shortx8 pack8v(floatx4 a, floatx4 b){
  shortx8 t;
  t[0]=(short)f2bf(a[0]); t[1]=(short)f2bf(a[1]); t[2]=(short)f2bf(a[2]); t[3]=(short)f2bf(a[3]);
  t[4]=(short)f2bf(b[0]); t[5]=(short)f2bf(b[1]); t[6]=(short)f2bf(b[2]); t[7]=(short)f2bf(b[3]);
  return t;
}

__device__ __forceinline__ void gload16(const void* g, void* l){
  __builtin_amdgcn_global_load_lds((const __attribute__((address_space(1))) void*)g,
                                   (__attribute__((address_space(3))) void*)l, 16, 0, 0);
}

// 256-thread staging of one [128][64] bf16 unit (swizzled image), CALLS per wave
template<int CALLS>
__device__ __forceinline__ void gstage(const char* src, size_t rowStrideB, int chunkByteOff,
                                       char* lds, int wid, int lane){
#pragma unroll
  for (int i=0;i<CALLS;++i){
    int base = (wid*CALLS + i)*1024;
    int off  = base + lane*16;
    int row  = off >> 7;
    int blk  = ((off >> 4) & 7) ^ (row & 7);
    gload16(src + (size_t)row*rowStrideB + chunkByteOff + blk*16, lds + base);
  }
}

__device__ __forceinline__ void lds_store4(char* buf, int row, int rowBytes, int khByte,
                                           int swzMask, const shortx8* v){
#pragma unroll
  for (int q=0;q<4;++q){
    int off = row*rowBytes + khByte + q*16;
    off ^= (row & swzMask) << 4;
    *(shortx8*)(buf + off) = v[q];
  }
}

__device__ __forceinline__ void stage_bf16(char* buf, const u16* gsrc, size_t srcRowBytes, int tid){
  int row = tid >> 1, kh = tid & 1;
  const char* p = (const char*)gsrc + (size_t)row*srcRowBytes + kh*64;
  shortx8 v[4];
#pragma unroll
  for (int q=0;q<4;++q) v[q] = *(const shortx8*)(p + q*16);
  lds_store4(buf, row, 128, kh*64, 7, v);
}

__device__ __forceinline__ shortx8 lds_frag(const char* buf, int row, int rowBytes, int kByte,
                                            int swzMask, int lane){
  int off = row*rowBytes + kByte + ((lane>>4)<<4);
  off ^= (row & swzMask) << 4;
  return *(const shortx8*)(buf + off);
}

template<int MF, int NF>
__device__ __forceinline__ void mma64(const char* As, const char* Bs, int wm, int wn, int lane,
                                      floatx4 acc[MF][NF]){
#pragma unroll
  for (int kk=0; kk<2; ++kk){
    shortx8 a[MF], b[NF];
#pragma unroll
    for (int i=0;i<MF;++i) a[i] = lds_frag(As, wm + i*16 + (lane&15), 128, kk*64, 7, lane);
#pragma unroll
    for (int j=0;j<NF;++j) b[j] = lds_frag(Bs, wn + j*16 + (lane&15), 128, kk*64, 7, lane);
#pragma unroll
    for (int i=0;i<MF;++i)
#pragma unroll
      for (int j=0;j<NF;++j)
        acc[i][j] = __builtin_amdgcn_mfma_f32_16x16x32_bf16(a[i], b[j], acc[i][j], 0, 0, 0);
  }
}

// main-loop body for the 256x256 kernels: per-kk frag load + MFMA
__device__ __forceinline__ void mma_256tile(const char* Ab, const char* Bb, int wm, int wn,
                                            int lane, floatx4 acc[8][4]){
#pragma unroll
  for (int kk=0;kk<2;++kk){
    shortx8 a[8], b[4];
#pragma unroll
    for (int i=0;i<8;++i) a[i] = lds_frag(Ab, wm + i*16 + (lane&15), 128, kk*64, 7, lane);
#pragma unroll
    for (int j=0;j<4;++j) b[j] = lds_frag(Bb, wn + j*16 + (lane&15), 128, kk*64, 7, lane);
    __builtin_amdgcn_s_setprio(1);
#pragma unroll
    for (int i=0;i<8;++i)
#pragma unroll
      for (int j=0;j<4;++j)
        acc[i][j] = __builtin_amdgcn_mfma_f32_16x16x32_bf16(a[i], b[j], acc[i][j], 0, 0, 0);
    __builtin_amdgcn_s_setprio(0);
  }
}

// bijective XCD chunking (nwg % 8 == 0)
__device__ __forceinline__ int xcd_swz(int bid, int nwg){
  int q = nwg >> 3;
  return (bid & 7)*q + (bid >> 3);
}

// ---------- prep ----------
__global__ __launch_bounds__(256) void transpose_w2(const float* __restrict__ src,
                                                    u16* __restrict__ dst,
                                                    int sKstride, int kSrcOff, int Kuse,
                                                    int N, int Kpad, int kDstOff){
  __shared__ float tile[32][33];
  int s = blockIdx.z;
  int k0 = blockIdx.x*32, n0 = blockIdx.y*32;
  int tx = threadIdx.x & 31, ty = threadIdx.x >> 5;
#pragma unroll
  for (int r=0;r<4;++r){
    int k = k0 + ty*4 + r;
    float v = (k < Kuse) ? src[((size_t)s*sKstride + kSrcOff + k)*N + n0 + tx] : 0.f;
    tile[ty*4+r][tx] = v;
  }
  __syncthreads();
#pragma unroll
  for (int r=0;r<4;++r){
    int n = n0 + ty*4 + r;
    dst[((size_t)s*N + n)*Kpad + kDstOff + k0 + tx] = f2bf(tile[tx][ty*4+r]);
  }
}

// ---------- bn (unchanged): h2b + gsb side-write ----------
__global__ __launch_bounds__(256) void k_bn(const float* __restrict__ gs,
     const u16* __restrict__ w1t, const u16* __restrict__ w2t,
     const float* __restrict__ b1, const float* __restrict__ b2,
     u16* __restrict__ h2b, u16* __restrict__ gsb){
  __shared__ __align__(16) char SMB[40960];
  int tid = threadIdx.x, lane = tid & 63, wid = tid >> 6;
  int nb = xcd_swz(blockIdx.x, 1152);
  int m0 = (nb & 63)*128, s = nb >> 6;
  floatx4 acc[2][2] = {};
  const char*  Bsrc = (const char*)w1t + (size_t)s*32*1024;
  size_t rowIdx = ((size_t)(m0 + (tid>>1))*SS + s)*DD + (tid&1)*32;
  const float* Ags  = gs + rowIdx;
  u16*         Gsb  = gsb + rowIdx;
  floatx4 fr[8];
  gstage<1>(Bsrc, 1024, 0, SMB+32768, wid, lane);
#pragma unroll
  for (int q=0;q<8;++q) fr[q] = *(const floatx4*)(Ags + q*4);
  for (int c=0;c<8;++c){
    char* Asc = SMB + (c&1)*16384;
    char* Bsc = SMB + 32768 + (c&1)*4096;
    { shortx8 v[4];
#pragma unroll
      for (int q=0;q<4;++q) v[q] = pack8v(fr[2*q], fr[2*q+1]);
      u16* gp = Gsb + c*64;
#pragma unroll
      for (int q=0;q<4;++q) *(shortx8*)(gp + q*8) = v[q];
      lds_store4(Asc, tid>>1, 128, (tid&1)*64, 7, v); }
    __syncthreads();
    int cn = c+1;
    if (cn < 8){
      gstage<1>(Bsrc, 1024, cn*128, SMB + 32768 + (cn&1)*4096, wid, lane);
      const float* p = Ags + cn*64;
#pragma unroll
      for (int q=0;q<8;++q) fr[q] = *(const floatx4*)(p + q*4);
    }
    mma64<2,2>(Asc, Bsc, wid*32, 0, lane, acc);
  }
  __syncthreads();
  char* G1  = SMB;
  char* W2s = SMB + 8192;
#pragma unroll
  for (int i=0;i<2;++i)
#pragma unroll
   for (int j=0;j<2;++j){
    int col = j*16 + (lane&15);
    float bias = b1[s*32 + col];
#pragma unroll
    for (int r=0;r<4;++r){
      int row = wid*32 + i*16 + ((lane>>4)<<2) + r;
      float v = fmaxf(acc[i][j][r] + bias, 0.f);
      int off = (row*64 + col*2) ^ ((row&3)<<4);
      *(u16*)(G1 + off) = f2bf(v);
    }
  }
  if (tid < 32){
    const u16* p = w2t + (size_t)s*32*32 + tid*32;
#pragma unroll
    for (int q=0;q<4;++q){
      int off = (tid*64 + q*16) ^ ((tid&3)<<4);
      *(shortx8*)(W2s + off) = *(const shortx8*)(p + q*8);
    }
  }
  __syncthreads();
  floatx4 acc2[2][2] = {};
  {
    shortx8 a[2], b[2];
#pragma unroll
    for (int i=0;i<2;++i) a[i] = lds_frag(G1,  wid*32 + i*16 + (lane&15), 64, 0, 3, lane);
#pragma unroll
    for (int j=0;j<2;++j) b[j] = lds_frag(W2s, j*16 + (lane&15),          64, 0, 3, lane);
#pragma unroll
    for (int i=0;i<2;++i)
#pragma unroll
      for (int j=0;j<2;++j)
        acc2[i][j] = __builtin_amdgcn_mfma_f32_16x16x32_bf16(a[i], b[j], acc2[i][j], 0,0,0);
  }
#pragma unroll
  for (int i=0;i<2;++i)
#pragma unroll
   for (int j=0;j<2;++j){
    int col = j*16 + (lane&15);
    float bias = b2[s*32 + col];
#pragma unroll
    for (int r=0;r<4;++r){
      int row = wid*32 + i*16 + ((lane>>4)<<2) + r;
      h2b[((size_t)(m0+row)*SS + s)*32 + col] = f2bf(acc2[i][j][r] + bias);
    }
  }
}

// ---------- gm + age (unchanged) ----------
__global__ __launch_bounds__(256) void k_gm(const u16* __restrict__ h2b,
     const u16* __restrict__ w1t, const u16* __restrict__ w2t,
     const float* __restrict__ b1, const float* __restrict__ b2,
     const float* __restrict__ ta, const float* __restrict__ aw1, const float* __restrict__ ab1,
     const float* __restrict__ aw2, const float* __restrict__ ab2,
     u16* __restrict__ gfab){
  __shared__ __align__(16) char As[128*128];
  __shared__ __align__(16) char Bs[128*128];
  __shared__ __align__(16) char G1[128*256];
  int tid=threadIdx.x, lane=tid&63, w=tid>>6;
  int m0 = blockIdx.x*128;
  floatx4 acc[2][8] = {};
  for (int c=0;c<9;++c){
    __syncthreads();
    stage_bf16(As, h2b + (size_t)m0*576 + c*64, 1152, tid);
    stage_bf16(Bs, w1t + c*64,                 1152, tid);
    __syncthreads();
    mma64<2,8>(As, Bs, w*32, 0, lane, acc);
  }
#pragma unroll
  for (int i=0;i<2;++i)
#pragma unroll
   for (int j=0;j<8;++j){
    int col = j*16 + (lane&15);
    float bias = b1[col];
#pragma unroll
    for (int r=0;r<4;++r){
      int row = w*32 + i*16 + ((lane>>4)<<2) + r;
      float v = fmaxf(acc[i][j][r] + bias, 0.f);
      int off = (row*256 + col*2) ^ ((row&7)<<4);
      *(u16*)(G1 + off) = f2bf(v);
    }
  }
  floatx4 acc2[2][8] = {};
  for (int c2=0;c2<2;++c2){
    __syncthreads();
    stage_bf16(Bs, w2t + c2*64, 256, tid);
    __syncthreads();
#pragma unroll
    for (int kk=0;kk<2;++kk){
      shortx8 a[2], b[8];
#pragma unroll
      for (int i=0;i<2;++i){
        int row = w*32 + i*16 + (lane&15);
        int off = (row*256 + c2*128 + kk*64 + ((lane>>4)<<4)) ^ ((row&7)<<4);
        a[i] = *(const shortx8*)(G1 + off);
      }
#pragma unroll
      for (int j=0;j<8;++j) b[j] = lds_frag(Bs, j*16 + (lane&15), 128, kk*64, 7, lane);
#pragma unroll
      for (int i=0;i<2;++i)
#pragma unroll
        for (int j=0;j<8;++j)
          acc2[i][j] = __builtin_amdgcn_mfma_f32_16x16x32_bf16(a[i], b[j], acc2[i][j], 0,0,0);
    }
  }
#pragma unroll
  for (int i=0;i<2;++i)
#pragma unroll
   for (int j=0;j<8;++j){
    int col = j*16 + (lane&15);
    float bias = b2[col];
#pragma unroll
    for (int r=0;r<4;++r){
      int row = w*32 + i*16 + ((lane>>4)<<2) + r;
      gfab[(size_t)(m0+row)*192 + col] = f2bf(acc2[i][j][r] + bias);
    }
  }
  if (tid < 128){
    int bidx = m0 + tid;
    float t = ta[bidx];
    float a1[16];
#pragma unroll
    for (int j2=0;j2<16;++j2){ float v = t*aw1[j2] + ab1[j2]; a1[j2] = fmaxf(v, 0.f); }
#pragma unroll
    for (int m=0;m<16;++m){
      float v = ab2[m];
#pragma unroll
      for (int j2=0;j2<16;++j2) v += a1[j2]*aw2[j2*16+m];
      gfab[(size_t)bidx*192 + 128 + m] = f2bf(v);
    }
    shortx8 zz = {};
#pragma unroll
    for (int z=0;z<6;++z) *(shortx8*)(gfab + (size_t)bidx*192 + 144 + z*8) = zz;
  }
}

// ---------- fc1: 256x256 tile, 8 waves, fully-unrolled counted-vmcnt pipeline ----------
__global__ __launch_bounds__(512, 2) void k_fc1(const u16* __restrict__ gfab,
     const u16* __restrict__ gsb, const u16* __restrict__ w1t,
     const float* __restrict__ b1, u16* __restrict__ y1b){
  __shared__ __align__(16) char SMB[131072];  // A dbuf 2x32K @0, B dbuf 2x32K @65536
  int tid=threadIdx.x, lane=tid&63, wid=tid>>6;
  int nb = xcd_swz(blockIdx.x, 1152);
  int n1 = nb&1, m0 = ((nb>>1)&31)*256, s = nb>>6;
  int wm = (wid>>2)*128, wn = (wid&3)*64;
  floatx4 acc[8][4] = {};
  // hoisted per-lane staging state
  int r0 = (wid*2)*8 + (lane>>3), r1 = r0 + 8;
  int x0 = ((lane&7)^(r0&7))<<4,  x1 = ((lane&7)^(r1&7))<<4;
  int LD0 = (wid*2)*1024, LD1 = LD0+1024, LD2 = LD0+16384, LD3 = LD1+16384;
  const char* gA = (const char*)gfab + (size_t)m0*384;
  const size_t SL = (size_t)SS*1024;
  const char* gL = (const char*)gsb + ((size_t)m0*SS + s)*1024;
  const char* gB = (const char*)w1t + ((size_t)s*512 + n1*256)*1408;
  const char *pG0 = gA + (size_t)r0*384 + x0,        *pG1 = gA + (size_t)r1*384 + x1;
  const char *pG2 = gA + (size_t)(128+r0)*384 + x0,  *pG3 = gA + (size_t)(128+r1)*384 + x1;
  const char *pL0 = gL + (size_t)r0*SL + x0,         *pL1 = gL + (size_t)r1*SL + x1;
  const char *pL2 = gL + (size_t)(128+r0)*SL + x0,   *pL3 = gL + (size_t)(128+r1)*SL + x1;
  const char *pB0 = gB + (size_t)r0*1408 + x0,       *pB1 = gB + (size_t)r1*1408 + x1;
  const char *pB2 = gB + (size_t)(128+r0)*1408 + x0, *pB3 = gB + (size_t)(128+r1)*1408 + x1;
#define F1A(t) do{ char* _l = SMB + ((t)&1)*32768; \
    if ((t)<3){ gload16(pG0+(t)*128,_l+LD0); gload16(pG1+(t)*128,_l+LD1); \
                gload16(pG2+(t)*128,_l+LD2); gload16(pG3+(t)*128,_l+LD3); } \
    else      { gload16(pL0+((t)-3)*128,_l+LD0); gload16(pL1+((t)-3)*128,_l+LD1); \
                gload16(pL2+((t)-3)*128,_l+LD2); gload16(pL3+((t)-3)*128,_l+LD3); } }while(0)
#define F1B(t) do{ char* _l = SMB + 65536 + ((t)&1)*32768; \
    gload16(pB0+(t)*128,_l+LD0); gload16(pB1+(t)*128,_l+LD1); \
    gload16(pB2+(t)*128,_l+LD2); gload16(pB3+(t)*128,_l+LD3); }while(0)
  F1A(0); F1B(0); F1A(1); F1B(1);
#pragma unroll
  for (int c=0;c<11;++c){
    if (c<10) asm volatile("s_waitcnt vmcnt(8)" ::: "memory");
    else      asm volatile("s_waitcnt vmcnt(0)" ::: "memory");
    __builtin_amdgcn_s_barrier();
    __builtin_amdgcn_sched_barrier(0);
    mma_256tile(SMB + (c&1)*32768, SMB + 65536 + (c&1)*32768, wm, wn, lane, acc);
    asm volatile("s_waitcnt lgkmcnt(0)" ::: "memory");
    __builtin_amdgcn_s_barrier();
    __builtin_amdgcn_sched_barrier(0);
    if (c+2<11){ F1A(c+2); F1B(c+2); }
  }
  __syncthreads();
  // epilogue: relu+bias -> SMB [256][512B bf16] swizzled, then coalesced stores
#pragma unroll
  for (int i=0;i<8;++i)
#pragma unroll
   for (int j=0;j<4;++j){
    int col = wn + j*16 + (lane&15);
    float bias = b1[(size_t)s*512 + n1*256 + col];
#pragma unroll
    for (int r=0;r<4;++r){
      int row = wm + i*16 + ((lane>>4)<<2) + r;
      float v = fmaxf(acc[i][j][r] + bias, 0.f);
      int off = (row*512 + col*2) ^ ((row&7)<<4);
      *(u16*)(SMB + off) = f2bf(v);
    }
  }
  __syncthreads();
  {
    int row = tid>>1, half = tid&1;
    u16* gp = y1b + ((size_t)(m0+row)*SS + s)*DD + n1*256 + half*128;
#pragma unroll
    for (int q=0;q<16;++q){
      int off = (row*512 + half*256 + q*16) ^ ((row&7)<<4);
      *(shortx8*)(gp + q*8) = *(const shortx8*)(SMB + off);
    }
  }
}

// ---------- fc2: 256x256 tile, 8 waves, fully-unrolled counted-vmcnt pipeline ----------
__global__ __launch_bounds__(512, 2) void k_fc2(const u16* __restrict__ y1b,
     const u16* __restrict__ gsb, const u16* __restrict__ w2t,
     const float* __restrict__ b2, float* __restrict__ out){
  __shared__ __align__(16) char SMB[131072];
  int tid=threadIdx.x, lane=tid&63, wid=tid>>6;
  int nb = xcd_swz(blockIdx.x, 1152);
  int n1 = nb&1, m0 = ((nb>>1)&31)*256, s = nb>>6;
  int wm = (wid>>2)*128, wn = (wid&3)*64;
  floatx4 acc[8][4] = {};
  int r0 = (wid*2)*8 + (lane>>3), r1 = r0 + 8;
  int x0 = ((lane&7)^(r0&7))<<4,  x1 = ((lane&7)^(r1&7))<<4;
  int LD0 = (wid*2)*1024, LD1 = LD0+1024, LD2 = LD0+16384, LD3 = LD1+16384;
  const size_t SL = (size_t)SS*1024;
  const char* gY = (const char*)y1b + ((size_t)m0*SS + s)*1024;
  const char* gW = (const char*)w2t + ((size_t)s*512 + n1*256)*1024;
  const char *pY0 = gY + (size_t)r0*SL + x0,         *pY1 = gY + (size_t)r1*SL + x1;
  const char *pY2 = gY + (size_t)(128+r0)*SL + x0,   *pY3 = gY + (size_t)(128+r1)*SL + x1;
  const char *pW0 = gW + (size_t)r0*1024 + x0,       *pW1 = gW + (size_t)r1*1024 + x1;
  const char *pW2 = gW + (size_t)(128+r0)*1024 + x0, *pW3 = gW + (size_t)(128+r1)*1024 + x1;
#define F2A(t) do{ char* _l = SMB + ((t)&1)*32768; \
    gload16(pY0+(t)*128,_l+LD0); gload16(pY1+(t)*128,_l+LD1); \
    gload16(pY2+(t)*128,_l+LD2); gload16(pY3+(t)*128,_l+LD3); }while(0)
#define F2B(t) do{ char* _l = SMB + 65536 + ((t)&1)*32768; \
    gload16(pW0+(t)*128,_l+LD0); gload16(pW1+(t)*128,_l+LD1); \
    gload16(pW2+(t)*128,_l+LD2); gload16(pW3+(t)*128,_l+LD3); }while(0)
  F2A(0); F2B(0); F2A(1); F2B(1);
#pragma unroll
  for (int c=0;c<8;++c){
    if (c<7) asm volatile("s_waitcnt vmcnt(8)" ::: "memory");
    else     asm volatile("s_waitcnt vmcnt(0)" ::: "memory");
    __builtin_amdgcn_s_barrier();
    __builtin_amdgcn_sched_barrier(0);
    mma_256tile(SMB + (c&1)*32768, SMB + 65536 + (c&1)*32768, wm, wn, lane, acc);
    asm volatile("s_waitcnt lgkmcnt(0)" ::: "memory");
    __builtin_amdgcn_s_barrier();
    __builtin_amdgcn_sched_barrier(0);
    if (c+2<8){ F2A(c+2); F2B(c+2); }
  }
  // epilogue in two row-halves via fp32 LDS [128][1024B]
  float* SMF = (float*)SMB;
#pragma unroll 1
  for (int h=0;h<2;++h){
    __syncthreads();
    if ((wid>>2) == h){
#pragma unroll
      for (int i=0;i<8;++i)
#pragma unroll
       for (int j=0;j<4;++j){
        int col = wn + j*16 + (lane&15);
#pragma unroll
        for (int r=0;r<4;++r){
          int rl = i*16 + ((lane>>4)<<2) + r;
          int off = (rl*1024 + col*4) ^ ((rl&7)<<4);
          *(float*)((char*)SMF + off) = acc[i][j][r];
        }
      }
    }
    __syncthreads();
    {
      int rl = tid>>2, quarter = tid&3;
      int grow = m0 + h*128 + rl;
      size_t gidx = ((size_t)grow*SS + s)*DD + n1*256 + quarter*64;
      const float* bp = b2 + (size_t)s*512 + n1*256 + quarter*64;
      const u16*   gp = gsb + gidx;
#pragma unroll
      for (int q2=0;q2<8;++q2){
        shortx8 gv = *(const shortx8*)(gp + q2*8);
        int off0 = (rl*1024 + quarter*256 + q2*32)      ^ ((rl&7)<<4);
        int off1 = (rl*1024 + quarter*256 + q2*32 + 16) ^ ((rl&7)<<4);
        floatx4 v0 = *(const floatx4*)((char*)SMF + off0);
        floatx4 v1 = *(const floatx4*)((char*)SMF + off1);
        floatx4 b0 = *(const floatx4*)(bp + q2*8);
        floatx4 b1v= *(const floatx4*)(bp + q2*8 + 4);
        floatx4 g0, g1;
        g0[0]=bf2f((u16)gv[0]); g0[1]=bf2f((u16)gv[1]); g0[2]=bf2f((u16)gv[2]); g0[3]=bf2f((u16)gv[3]);
        g1[0]=bf2f((u16)gv[4]); g1[1]=bf2f((u16)gv[5]); g1[2]=bf2f((u16)gv[6]); g1[3]=bf2f((u16)gv[7]);
        *(floatx4*)(out + gidx + q2*8)     = v0 + b0 + g0;
        *(floatx4*)(out + gidx + q2*8 + 4) = v1 + b1v + g1;
      }
    }
  }
}

// ---------- launch ----------
extern "C" void kernel_launch(void* const* d_in, const int* in_sizes, int n_in,
                              void* d_out, int out_size, void* d_ws, size_t ws_size,
                              hipStream_t stream){
  (void)in_sizes; (void)n_in; (void)out_size; (void)ws_size;
  const float* gs   = (const float*)d_in[1];
  const float* ta   = (const float*)d_in[2];
  const float* bnw1 = (const float*)d_in[3];
  const float* bnb1 = (const float*)d_in[4];
  const float* bnw2 = (const float*)d_in[5];
  const float* bnb2 = (const float*)d_in[6];
  const float* gmw1 = (const float*)d_in[7];
  const float* gmb1 = (const float*)d_in[8];
  const float* gmw2 = (const float*)d_in[9];
  const float* gmb2 = (const float*)d_in[10];
  const float* aw1  = (const float*)d_in[11];
  const float* ab1  = (const float*)d_in[12];
  const float* aw2  = (const float*)d_in[13];
  const float* ab2  = (const float*)d_in[14];
  const float* fcw1 = (const float*)d_in[15];
  const float* fcb1 = (const float*)d_in[16];
  const float* fcw2 = (const float*)d_in[17];
  const float* fcb2 = (const float*)d_in[18];

  char* ws = (char*)d_ws;
  u16* fcW1t = (u16*)(ws + 0);                  // 12,976,128
  u16* fcW2t = (u16*)(ws + 12976128);           //  9,437,184
  u16* bnW1t = (u16*)(ws + 22413312);           //    589,824
  u16* bnW2t = (u16*)(ws + 23003136);           //     36,864
  u16* gmW1t = (u16*)(ws + 23040000);           //    147,456
  u16* gmW2t = (u16*)(ws + 23187456);           //     32,768
  u16* h2b   = (u16*)(ws + 23220224);           //  9,437,184
  u16* gfab  = (u16*)(ws + 32657408);           //  3,145,728 (B x 192)
  u16* y1b   = (u16*)(ws + 35803136);           // 150,994,944
  u16* gsb   = (u16*)(ws + 186798080);          // 150,994,944 (end 337,793,024)
  float* out = (float*)d_out;

  dim3 blk(256);
  transpose_w2<<<dim3(16,1,18),  blk, 0, stream>>>(bnw1, bnW1t, 512, 0, 512,  32, 512, 0);
  transpose_w2<<<dim3(1,1,18),   blk, 0, stream>>>(bnw2, bnW2t,  32, 0,  32,  32,  32, 0);
  transpose_w2<<<dim3(18,4,1),   blk, 0, stream>>>(gmw1, gmW1t, 576, 0, 576, 128, 576, 0);
  transpose_w2<<<dim3(4,4,1),    blk, 0, stream>>>(gmw2, gmW2t, 128, 0, 128, 128, 128, 0);
  transpose_w2<<<dim3(6,16,18),  blk, 0, stream>>>(fcw1, fcW1t, 656, 0,   144, 512, 704, 0);
  transpose_w2<<<dim3(16,16,18), blk, 0, stream>>>(fcw1, fcW1t, 656, 144, 512, 512, 704, 192);
  transpose_w2<<<dim3(16,16,18), blk, 0, stream>>>(fcw2, fcW2t, 512, 0, 512, 512, 512, 0);

  k_bn <<<dim3(1152), blk,      0, stream>>>(gs, bnW1t, bnW2t, bnb1, bnb2, h2b, gsb);
  k_gm <<<dim3(64),   blk,      0, stream>>>(h2b, gmW1t, gmW2t, gmb1, gmb2, ta, aw1, ab1, aw2, ab2, gfab);
  k_fc1<<<dim3(1152), dim3(512), 0, stream>>>(gfab, gsb, fcW1t, fcb1, y1b);
  k_fc2<<<dim3(1152), dim3(512), 0, stream>>>(y1b, gsb, fcW2t, fcb2, out);
}

// Round 9
// 609.278 us; speedup vs baseline: 1.4940x; 1.4709x over previous
//
#include <hip/hip_runtime.h>

typedef unsigned short u16;
typedef unsigned int   u32;
typedef __attribute__((ext_vector_type(4))) float floatx4;
typedef __attribute__((ext_vector_type(8))) short shortx8;

#define BB 8192
#define SS 18
#define DD 512

// ---------- helpers ----------
__device__ __forceinline__ u16 f2bf(float f){            // RNE f32->bf16
  u32 u = __float_as_uint(f);
  return (u16)((u + 0x7FFFu + ((u >> 16) & 1u)) >> 16);
}
__device__ __forceinline__ float bf2f(u16 x){ return __uint_as_float(((u32)x)<<16); }

__device__ __forceinline__ shortx8 pack8v(floatx4 a, floatx4 b){
  shortx8 t;
  t[0]=(short)f2bf(a[0]); t[1]=(short)f2bf(a[1]); t[2]=(short)f2bf(a[2]); t[3]=(short)f2bf(a[3]);
  t[4]=(short)f2bf(b[0]); t[5]=(short)f2bf(b[1]); t[6]=(short)f2bf(b[2]); t[7]=(short)f2bf(b[3]);
  return t;
}

__device__ __forceinline__ void gload16(const void* g, void* l){
  __builtin_amdgcn_global_load_lds((const __attribute__((address_space(1))) void*)g,
                                   (__attribute__((address_space(3))) void*)l, 16, 0, 0);
}

template<int CALLS>
__device__ __forceinline__ void gstage(const char* src, size_t rowStrideB, int chunkByteOff,
                                       char* lds, int wid, int lane){
#pragma unroll
  for (int i=0;i<CALLS;++i){
    int base = (wid*CALLS + i)*1024;
    int off  = base + lane*16;
    int row  = off >> 7;
    int blk  = ((off >> 4) & 7) ^ (row & 7);
    gload16(src + (size_t)row*rowStrideB + chunkByteOff + blk*16, lds + base);
  }
}

__device__ __forceinline__ void lds_store4(char* buf, int row, int rowBytes, int khByte,
                                           int swzMask, const shortx8* v){
#pragma unroll
  for (int q=0;q<4;++q){
    int off = row*rowBytes + khByte + q*16;
    off ^= (row & swzMask) << 4;
    *(shortx8*)(buf + off) = v[q];
  }
}

__device__ __forceinline__ void stage_bf16(char* buf, const u16* gsrc, size_t srcRowBytes, int tid){
  int row = tid >> 1, kh = tid & 1;
  const char* p = (const char*)gsrc + (size_t)row*srcRowBytes + kh*64;
  shortx8 v[4];
#pragma unroll
  for (int q=0;q<4;++q) v[q] = *(const shortx8*)(p + q*16);
  lds_store4(buf, row, 128, kh*64, 7, v);
}

__device__ __forceinline__ shortx8 lds_frag(const char* buf, int row, int rowBytes, int kByte,
                                            int swzMask, int lane){
  int off = row*rowBytes + kByte + ((lane>>4)<<4);
  off ^= (row & swzMask) << 4;
  return *(const shortx8*)(buf + off);
}

template<int MF, int NF>
__device__ __forceinline__ void mma64(const char* As, const char* Bs, int wm, int wn, int lane,
                                      floatx4 acc[MF][NF]){
#pragma unroll
  for (int kk=0; kk<2; ++kk){
    shortx8 a[MF], b[NF];
#pragma unroll
    for (int i=0;i<MF;++i) a[i] = lds_frag(As, wm + i*16 + (lane&15), 128, kk*64, 7, lane);
#pragma unroll
    for (int j=0;j<NF;++j) b[j] = lds_frag(Bs, wn + j*16 + (lane&15), 128, kk*64, 7, lane);
#pragma unroll
    for (int i=0;i<MF;++i)
#pragma unroll
      for (int j=0;j<NF;++j)
        acc[i][j] = __builtin_amdgcn_mfma_f32_16x16x32_bf16(a[i], b[j], acc[i][j], 0, 0, 0);
  }
}

// split: ds_read all frags, then MFMA on regs
template<int MF, int NF>
__device__ __forceinline__ void frags_load(const char* As, const char* Bs, int wm, int wn, int lane,
                                           shortx8 a[2][MF], shortx8 b[2][NF]){
#pragma unroll
  for (int kk=0;kk<2;++kk){
#pragma unroll
    for (int i=0;i<MF;++i) a[kk][i] = lds_frag(As, wm + i*16 + (lane&15), 128, kk*64, 7, lane);
#pragma unroll
    for (int j=0;j<NF;++j) b[kk][j] = lds_frag(Bs, wn + j*16 + (lane&15), 128, kk*64, 7, lane);
  }
}
template<int MF, int NF>
__device__ __forceinline__ void frags_mma(shortx8 a[2][MF], shortx8 b[2][NF], floatx4 acc[MF][NF]){
  __builtin_amdgcn_s_setprio(1);
#pragma unroll
  for (int kk=0;kk<2;++kk)
#pragma unroll
    for (int i=0;i<MF;++i)
#pragma unroll
      for (int j=0;j<NF;++j)
        acc[i][j] = __builtin_amdgcn_mfma_f32_16x16x32_bf16(a[kk][i], b[kk][j], acc[i][j], 0, 0, 0);
  __builtin_amdgcn_s_setprio(0);
}

// bijective XCD chunking (nwg % 8 == 0)
__device__ __forceinline__ int xcd_swz(int bid, int nwg){
  int q = nwg >> 3;
  return (bid & 7)*q + (bid >> 3);
}

// ---------- prep ----------
__global__ __launch_bounds__(256) void transpose_w2(const float* __restrict__ src,
                                                    u16* __restrict__ dst,
                                                    int sKstride, int kSrcOff, int Kuse,
                                                    int N, int Kpad, int kDstOff){
  __shared__ float tile[32][33];
  int s = blockIdx.z;
  int k0 = blockIdx.x*32, n0 = blockIdx.y*32;
  int tx = threadIdx.x & 31, ty = threadIdx.x >> 5;
#pragma unroll
  for (int r=0;r<4;++r){
    int k = k0 + ty*4 + r;
    float v = (k < Kuse) ? src[((size_t)s*sKstride + kSrcOff + k)*N + n0 + tx] : 0.f;
    tile[ty*4+r][tx] = v;
  }
  __syncthreads();
#pragma unroll
  for (int r=0;r<4;++r){
    int n = n0 + ty*4 + r;
    dst[((size_t)s*N + n)*Kpad + kDstOff + k0 + tx] = f2bf(tile[tx][ty*4+r]);
  }
}

// ---------- bn (unchanged): h2b + gsb side-write ----------
__global__ __launch_bounds__(256) void k_bn(const float* __restrict__ gs,
     const u16* __restrict__ w1t, const u16* __restrict__ w2t,
     const float* __restrict__ b1, const float* __restrict__ b2,
     u16* __restrict__ h2b, u16* __restrict__ gsb){
  __shared__ __align__(16) char SMB[40960];
  int tid = threadIdx.x, lane = tid & 63, wid = tid >> 6;
  int nb = xcd_swz(blockIdx.x, 1152);
  int m0 = (nb & 63)*128, s = nb >> 6;
  floatx4 acc[2][2] = {};
  const char*  Bsrc = (const char*)w1t + (size_t)s*32*1024;
  size_t rowIdx = ((size_t)(m0 + (tid>>1))*SS + s)*DD + (tid&1)*32;
  const float* Ags  = gs + rowIdx;
  u16*         Gsb  = gsb + rowIdx;
  floatx4 fr[8];
  gstage<1>(Bsrc, 1024, 0, SMB+32768, wid, lane);
#pragma unroll
  for (int q=0;q<8;++q) fr[q] = *(const floatx4*)(Ags + q*4);
  for (int c=0;c<8;++c){
    char* Asc = SMB + (c&1)*16384;
    char* Bsc = SMB + 32768 + (c&1)*4096;
    { shortx8 v[4];
#pragma unroll
      for (int q=0;q<4;++q) v[q] = pack8v(fr[2*q], fr[2*q+1]);
      u16* gp = Gsb + c*64;
#pragma unroll
      for (int q=0;q<4;++q) *(shortx8*)(gp + q*8) = v[q];
      lds_store4(Asc, tid>>1, 128, (tid&1)*64, 7, v); }
    __syncthreads();
    int cn = c+1;
    if (cn < 8){
      gstage<1>(Bsrc, 1024, cn*128, SMB + 32768 + (cn&1)*4096, wid, lane);
      const float* p = Ags + cn*64;
#pragma unroll
      for (int q=0;q<8;++q) fr[q] = *(const floatx4*)(p + q*4);
    }
    mma64<2,2>(Asc, Bsc, wid*32, 0, lane, acc);
  }
  __syncthreads();
  char* G1  = SMB;
  char* W2s = SMB + 8192;
#pragma unroll
  for (int i=0;i<2;++i)
#pragma unroll
   for (int j=0;j<2;++j){
    int col = j*16 + (lane&15);
    float bias = b1[s*32 + col];
#pragma unroll
    for (int r=0;r<4;++r){
      int row = wid*32 + i*16 + ((lane>>4)<<2) + r;
      float v = fmaxf(acc[i][j][r] + bias, 0.f);
      int off = (row*64 + col*2) ^ ((row&3)<<4);
      *(u16*)(G1 + off) = f2bf(v);
    }
  }
  if (tid < 32){
    const u16* p = w2t + (size_t)s*32*32 + tid*32;
#pragma unroll
    for (int q=0;q<4;++q){
      int off = (tid*64 + q*16) ^ ((tid&3)<<4);
      *(shortx8*)(W2s + off) = *(const shortx8*)(p + q*8);
    }
  }
  __syncthreads();
  floatx4 acc2[2][2] = {};
  {
    shortx8 a[2], b[2];
#pragma unroll
    for (int i=0;i<2;++i) a[i] = lds_frag(G1,  wid*32 + i*16 + (lane&15), 64, 0, 3, lane);
#pragma unroll
    for (int j=0;j<2;++j) b[j] = lds_frag(W2s, j*16 + (lane&15),          64, 0, 3, lane);
#pragma unroll
    for (int i=0;i<2;++i)
#pragma unroll
      for (int j=0;j<2;++j)
        acc2[i][j] = __builtin_amdgcn_mfma_f32_16x16x32_bf16(a[i], b[j], acc2[i][j], 0,0,0);
  }
#pragma unroll
  for (int i=0;i<2;++i)
#pragma unroll
   for (int j=0;j<2;++j){
    int col = j*16 + (lane&15);
    float bias = b2[s*32 + col];
#pragma unroll
    for (int r=0;r<4;++r){
      int row = wid*32 + i*16 + ((lane>>4)<<2) + r;
      h2b[((size_t)(m0+row)*SS + s)*32 + col] = f2bf(acc2[i][j][r] + bias);
    }
  }
}

// ---------- gm + age (unchanged) ----------
__global__ __launch_bounds__(256) void k_gm(const u16* __restrict__ h2b,
     const u16* __restrict__ w1t, const u16* __restrict__ w2t,
     const float* __restrict__ b1, const float* __restrict__ b2,
     const float* __restrict__ ta, const float* __restrict__ aw1, const float* __restrict__ ab1,
     const float* __restrict__ aw2, const float* __restrict__ ab2,
     u16* __restrict__ gfab){
  __shared__ __align__(16) char As[128*128];
  __shared__ __align__(16) char Bs[128*128];
  __shared__ __align__(16) char G1[128*256];
  int tid=threadIdx.x, lane=tid&63, w=tid>>6;
  int m0 = blockIdx.x*128;
  floatx4 acc[2][8] = {};
  for (int c=0;c<9;++c){
    __syncthreads();
    stage_bf16(As, h2b + (size_t)m0*576 + c*64, 1152, tid);
    stage_bf16(Bs, w1t + c*64,                 1152, tid);
    __syncthreads();
    mma64<2,8>(As, Bs, w*32, 0, lane, acc);
  }
#pragma unroll
  for (int i=0;i<2;++i)
#pragma unroll
   for (int j=0;j<8;++j){
    int col = j*16 + (lane&15);
    float bias = b1[col];
#pragma unroll
    for (int r=0;r<4;++r){
      int row = w*32 + i*16 + ((lane>>4)<<2) + r;
      float v = fmaxf(acc[i][j][r] + bias, 0.f);
      int off = (row*256 + col*2) ^ ((row&7)<<4);
      *(u16*)(G1 + off) = f2bf(v);
    }
  }
  floatx4 acc2[2][8] = {};
  for (int c2=0;c2<2;++c2){
    __syncthreads();
    stage_bf16(Bs, w2t + c2*64, 256, tid);
    __syncthreads();
#pragma unroll
    for (int kk=0;kk<2;++kk){
      shortx8 a[2], b[8];
#pragma unroll
      for (int i=0;i<2;++i){
        int row = w*32 + i*16 + (lane&15);
        int off = (row*256 + c2*128 + kk*64 + ((lane>>4)<<4)) ^ ((row&7)<<4);
        a[i] = *(const shortx8*)(G1 + off);
      }
#pragma unroll
      for (int j=0;j<8;++j) b[j] = lds_frag(Bs, j*16 + (lane&15), 128, kk*64, 7, lane);
#pragma unroll
      for (int i=0;i<2;++i)
#pragma unroll
        for (int j=0;j<8;++j)
          acc2[i][j] = __builtin_amdgcn_mfma_f32_16x16x32_bf16(a[i], b[j], acc2[i][j], 0,0,0);
    }
  }
#pragma unroll
  for (int i=0;i<2;++i)
#pragma unroll
   for (int j=0;j<8;++j){
    int col = j*16 + (lane&15);
    float bias = b2[col];
#pragma unroll
    for (int r=0;r<4;++r){
      int row = w*32 + i*16 + ((lane>>4)<<2) + r;
      gfab[(size_t)(m0+row)*192 + col] = f2bf(acc2[i][j][r] + bias);
    }
  }
  if (tid < 128){
    int bidx = m0 + tid;
    float t = ta[bidx];
    float a1[16];
#pragma unroll
    for (int j2=0;j2<16;++j2){ float v = t*aw1[j2] + ab1[j2]; a1[j2] = fmaxf(v, 0.f); }
#pragma unroll
    for (int m=0;m<16;++m){
      float v = ab2[m];
#pragma unroll
      for (int j2=0;j2<16;++j2) v += a1[j2]*aw2[j2*16+m];
      gfab[(size_t)bidx*192 + 128 + m] = f2bf(v);
    }
    shortx8 zz = {};
#pragma unroll
    for (int z=0;z<6;++z) *(shortx8*)(gfab + (size_t)bidx*192 + 144 + z*8) = zz;
  }
}

// ---------- fc1: 128x256 tile, 8 waves, reg-queue A (3 deep) + LDS ring B (3 deep) ----------
__global__ __launch_bounds__(512, 2) void k_fc1(const u16* __restrict__ gfab,
     const u16* __restrict__ gsb, const u16* __restrict__ w1t,
     const float* __restrict__ b1, u16* __restrict__ y1b){
  __shared__ __align__(16) char SMB[131072];  // As 2x16KB @0, Bs 3x32KB @32768
  int tid=threadIdx.x, lane=tid&63, wid=tid>>6;
  int nb = xcd_swz(blockIdx.x, 2304);
  int n1 = nb&1, m0 = ((nb>>1)&63)*128, s = nb>>7;
  int wm = (wid>>2)*64, wn = (wid&3)*64;
  floatx4 acc[4][4] = {};
  // A reg-queue addressing: 4 thr/row, 32B each
  int ar = tid>>2, aq = (tid&3)*32;
  const char* pAg = (const char*)gfab + (size_t)(m0+ar)*384 + aq;
  const char* pAs = (const char*)gsb + ((size_t)(m0+ar)*SS + s)*1024 + aq;
  int wo0 = ar*128 + ( aq      ^ ((ar&7)<<4));
  int wo1 = ar*128 + ((aq+16)  ^ ((ar&7)<<4));
  // B glds pointers: 4 insts/wave over 256 rows
  const char* gW = (const char*)w1t + ((size_t)s*512 + n1*256)*1408;
  const char* pB[4]; int ldB[4];
#pragma unroll
  for (int i=0;i<4;++i){
    int base=(wid*4+i)*1024, off=base+lane*16;
    int row=off>>7, blk=((off>>4)&7)^(row&7);
    pB[i] = gW + (size_t)row*1408 + blk*16;
    ldB[i] = base;
  }
  floatx4 qA0[2], qA1[2], qA2[2];
#define QS1(c) ((c)%3==0?qA0:((c)%3==1?qA1:qA2))
#define LDA1(c,Q) do{ if((c)<3){ Q[0]=*(const floatx4*)(pAg+(c)*128); Q[1]=*(const floatx4*)(pAg+(c)*128+16); } \
                      else     { Q[0]=*(const floatx4*)(pAs+((c)-3)*128); Q[1]=*(const floatx4*)(pAs+((c)-3)*128+16); } }while(0)
#define ISSB1(c) do{ char* _d=SMB+32768+((c)%3)*32768; \
    gload16(pB[0]+(c)*128,_d+ldB[0]); gload16(pB[1]+(c)*128,_d+ldB[1]); \
    gload16(pB[2]+(c)*128,_d+ldB[2]); gload16(pB[3]+(c)*128,_d+ldB[3]); }while(0)
  LDA1(0,qA0); __builtin_amdgcn_sched_barrier(0);
  ISSB1(0);    __builtin_amdgcn_sched_barrier(0);
  LDA1(1,qA1); __builtin_amdgcn_sched_barrier(0);
  ISSB1(1);    __builtin_amdgcn_sched_barrier(0);
  LDA1(2,qA2); __builtin_amdgcn_sched_barrier(0);
#pragma unroll
  for (int c=0;c<11;++c){
    if (c<9)       asm volatile("s_waitcnt vmcnt(8)" ::: "memory");
    else if (c==9) asm volatile("s_waitcnt vmcnt(6)" ::: "memory");
    else           asm volatile("s_waitcnt vmcnt(0)" ::: "memory");
    { char* As = SMB + (c&1)*16384;
      const floatx4* Q = QS1(c);
      *(floatx4*)(As+wo0) = Q[0]; *(floatx4*)(As+wo1) = Q[1]; }
    asm volatile("s_waitcnt lgkmcnt(0)" ::: "memory");
    __builtin_amdgcn_s_barrier();
    shortx8 a[2][4], b[2][4];
    frags_load<4,4>(SMB + (c&1)*16384, SMB + 32768 + (c%3)*32768, wm, wn, lane, a, b);
    __builtin_amdgcn_sched_barrier(0);
    if (c+2<11) ISSB1(c+2);
    if (c+3<11) { LDA1(c+3, QS1(c+3)); }
    __builtin_amdgcn_sched_barrier(0);
    frags_mma<4,4>(a, b, acc);
  }
  __syncthreads();
  // epilogue: relu+bias -> SMB [128][512B] bf16 swizzled, then coalesced stores
#pragma unroll
  for (int i=0;i<4;++i)
#pragma unroll
   for (int j=0;j<4;++j){
    int col = wn + j*16 + (lane&15);
    float bias = b1[(size_t)s*512 + n1*256 + col];
#pragma unroll
    for (int r=0;r<4;++r){
      int row = wm + i*16 + ((lane>>4)<<2) + r;
      float v = fmaxf(acc[i][j][r] + bias, 0.f);
      int off = (row*512 + col*2) ^ ((row&7)<<4);
      *(u16*)(SMB + off) = f2bf(v);
    }
  }
  __syncthreads();
  {
    int row = tid>>2, cq = tid&3;
    u16* gp = y1b + ((size_t)(m0+row)*SS + s)*DD + n1*256 + cq*64;
#pragma unroll
    for (int q=0;q<8;++q){
      int off = (row*512 + cq*128 + q*16) ^ ((row&7)<<4);
      *(shortx8*)(gp + q*8) = *(const shortx8*)(SMB + off);
    }
  }
}

// ---------- fc2: 128x256 tile, 8 waves, reg-queue A + LDS ring B; out = y1 @ w2 + b2 + gs ----------
__global__ __launch_bounds__(512, 2) void k_fc2(const u16* __restrict__ y1b,
     const u16* __restrict__ gsb, const u16* __restrict__ w2t,
     const float* __restrict__ b2, float* __restrict__ out){
  __shared__ __align__(16) char SMB[131072];  // As 2x16KB @0, Bs 3x32KB @32768
  int tid=threadIdx.x, lane=tid&63, wid=tid>>6;
  int nb = xcd_swz(blockIdx.x, 2304);
  int n1 = nb&1, m0 = ((nb>>1)&63)*128, s = nb>>7;
  int wm = (wid>>2)*64, wn = (wid&3)*64;
  floatx4 acc[4][4] = {};
  int ar = tid>>2, aq = (tid&3)*32;
  const char* pA = (const char*)y1b + ((size_t)(m0+ar)*SS + s)*1024 + aq;
  int wo0 = ar*128 + ( aq      ^ ((ar&7)<<4));
  int wo1 = ar*128 + ((aq+16)  ^ ((ar&7)<<4));
  const char* gW = (const char*)w2t + ((size_t)s*512 + n1*256)*1024;
  const char* pB[4]; int ldB[4];
#pragma unroll
  for (int i=0;i<4;++i){
    int base=(wid*4+i)*1024, off=base+lane*16;
    int row=off>>7, blk=((off>>4)&7)^(row&7);
    pB[i] = gW + (size_t)row*1024 + blk*16;
    ldB[i] = base;
  }
  floatx4 qA0[2], qA1[2], qA2[2];
#define QS2(c) ((c)%3==0?qA0:((c)%3==1?qA1:qA2))
#define LDA2(c,Q) do{ Q[0]=*(const floatx4*)(pA+(c)*128); Q[1]=*(const floatx4*)(pA+(c)*128+16); }while(0)
#define ISSB2(c) do{ char* _d=SMB+32768+((c)%3)*32768; \
    gload16(pB[0]+(c)*128,_d+ldB[0]); gload16(pB[1]+(c)*128,_d+ldB[1]); \
    gload16(pB[2]+(c)*128,_d+ldB[2]); gload16(pB[3]+(c)*128,_d+ldB[3]); }while(0)
  LDA2(0,qA0); __builtin_amdgcn_sched_barrier(0);
  ISSB2(0);    __builtin_amdgcn_sched_barrier(0);
  LDA2(1,qA1); __builtin_amdgcn_sched_barrier(0);
  ISSB2(1);    __builtin_amdgcn_sched_barrier(0);
  LDA2(2,qA2); __builtin_amdgcn_sched_barrier(0);
#pragma unroll
  for (int c=0;c<8;++c){
    if (c<6)       asm volatile("s_waitcnt vmcnt(8)" ::: "memory");
    else if (c==6) asm volatile("s_waitcnt vmcnt(6)" ::: "memory");
    else           asm volatile("s_waitcnt vmcnt(0)" ::: "memory");
    { char* As = SMB + (c&1)*16384;
      const floatx4* Q = QS2(c);
      *(floatx4*)(As+wo0) = Q[0]; *(floatx4*)(As+wo1) = Q[1]; }
    asm volatile("s_waitcnt lgkmcnt(0)" ::: "memory");
    __builtin_amdgcn_s_barrier();
    shortx8 a[2][4], b[2][4];
    frags_load<4,4>(SMB + (c&1)*16384, SMB + 32768 + (c%3)*32768, wm, wn, lane, a, b);
    __builtin_amdgcn_sched_barrier(0);
    if (c+2<8) ISSB2(c+2);
    if (c+3<8) { LDA2(c+3, QS2(c+3)); }
    __builtin_amdgcn_sched_barrier(0);
    frags_mma<4,4>(a, b, acc);
  }
  // epilogue: two m-half phases via fp32 LDS [64 rows][1024B] swizzled
  float* SMF = (float*)SMB;
#pragma unroll 1
  for (int h=0;h<2;++h){
    __syncthreads();
    if ((wid>>2) == h){
#pragma unroll
      for (int i=0;i<4;++i)
#pragma unroll
       for (int j=0;j<4;++j){
        int col = wn + j*16 + (lane&15);
#pragma unroll
        for (int r=0;r<4;++r){
          int rl = i*16 + ((lane>>4)<<2) + r;
          int off = (rl*1024 + col*4) ^ ((rl&7)<<4);
          *(float*)((char*)SMF + off) = acc[i][j][r];
        }
      }
    }
    __syncthreads();
    {
      int rl = tid>>3, c8 = tid&7;
      int grow = m0 + h*64 + rl;
      size_t gidx = ((size_t)grow*SS + s)*DD + n1*256 + c8*32;
      const float* bp = b2 + (size_t)s*512 + n1*256 + c8*32;
      const u16*   gp = gsb + gidx;
      shortx8 gv[4];
#pragma unroll
      for (int q=0;q<4;++q) gv[q] = *(const shortx8*)(gp + q*8);
#pragma unroll
      for (int q=0;q<8;++q){
        int off = (rl*1024 + c8*128 + q*16) ^ ((rl&7)<<4);
        floatx4 v = *(const floatx4*)((char*)SMF + off);
        floatx4 bb = *(const floatx4*)(bp + q*4);
        floatx4 g;
        g[0]=bf2f((u16)gv[q>>1][(q&1)*4+0]); g[1]=bf2f((u16)gv[q>>1][(q&1)*4+1]);
        g[2]=bf2f((u16)gv[q>>1][(q&1)*4+2]); g[3]=bf2f((u16)gv[q>>1][(q&1)*4+3]);
        *(floatx4*)(out + gidx + q*4) = v + bb + g;
      }
    }
  }
}

// ---------- launch ----------
extern "C" void kernel_launch(void* const* d_in, const int* in_sizes, int n_in,
                              void* d_out, int out_size, void* d_ws, size_t ws_size,
                              hipStream_t stream){
  (void)in_sizes; (void)n_in; (void)out_size; (void)ws_size;
  const float* gs   = (const float*)d_in[1];
  const float* ta   = (const float*)d_in[2];
  const float* bnw1 = (const float*)d_in[3];
  const float* bnb1 = (const float*)d_in[4];
  const float* bnw2 = (const float*)d_in[5];
  const float* bnb2 = (const float*)d_in[6];
  const float* gmw1 = (const float*)d_in[7];
  const float* gmb1 = (const float*)d_in[8];
  const float* gmw2 = (const float*)d_in[9];
  const float* gmb2 = (const float*)d_in[10];
  const float* aw1  = (const float*)d_in[11];
  const float* ab1  = (const float*)d_in[12];
  const float* aw2  = (const float*)d_in[13];
  const float* ab2  = (const float*)d_in[14];
  const float* fcw1 = (const float*)d_in[15];
  const float* fcb1 = (const float*)d_in[16];
  const float* fcw2 = (const float*)d_in[17];
  const float* fcb2 = (const float*)d_in[18];

  char* ws = (char*)d_ws;
  u16* fcW1t = (u16*)(ws + 0);                  // 12,976,128
  u16* fcW2t = (u16*)(ws + 12976128);           //  9,437,184
  u16* bnW1t = (u16*)(ws + 22413312);           //    589,824
  u16* bnW2t = (u16*)(ws + 23003136);           //     36,864
  u16* gmW1t = (u16*)(ws + 23040000);           //    147,456
  u16* gmW2t = (u16*)(ws + 23187456);           //     32,768
  u16* h2b   = (u16*)(ws + 23220224);           //  9,437,184
  u16* gfab  = (u16*)(ws + 32657408);           //  3,145,728 (B x 192)
  u16* y1b   = (u16*)(ws + 35803136);           // 150,994,944
  u16* gsb   = (u16*)(ws + 186798080);          // 150,994,944 (end 337,793,024)
  float* out = (float*)d_out;

  dim3 blk(256);
  transpose_w2<<<dim3(16,1,18),  blk, 0, stream>>>(bnw1, bnW1t, 512, 0, 512,  32, 512, 0);
  transpose_w2<<<dim3(1,1,18),   blk, 0, stream>>>(bnw2, bnW2t,  32, 0,  32,  32,  32, 0);
  transpose_w2<<<dim3(18,4,1),   blk, 0, stream>>>(gmw1, gmW1t, 576, 0, 576, 128, 576, 0);
  transpose_w2<<<dim3(4,4,1),    blk, 0, stream>>>(gmw2, gmW2t, 128, 0, 128, 128, 128, 0);
  transpose_w2<<<dim3(6,16,18),  blk, 0, stream>>>(fcw1, fcW1t, 656, 0,   144, 512, 704, 0);
  transpose_w2<<<dim3(16,16,18), blk, 0, stream>>>(fcw1, fcW1t, 656, 144, 512, 512, 704, 192);
  transpose_w2<<<dim3(16,16,18), blk, 0, stream>>>(fcw2, fcW2t, 512, 0, 512, 512, 512, 0);

  k_bn <<<dim3(1152), blk,       0, stream>>>(gs, bnW1t, bnW2t, bnb1, bnb2, h2b, gsb);
  k_gm <<<dim3(64),   blk,       0, stream>>>(h2b, gmW1t, gmW2t, gmb1, gmb2, ta, aw1, ab1, aw2, ab2, gfab);
  k_fc1<<<dim3(2304), dim3(512), 0, stream>>>(gfab, gsb, fcW1t, fcb1, y1b);
  k_fc2<<<dim3(2304), dim3(512), 0, stream>>>(y1b, gsb, fcW2t, fcb2, out);
}

// Round 11
// 584.810 us; speedup vs baseline: 1.5566x; 1.0418x over previous
//
#include <hip/hip_runtime.h>

typedef unsigned short u16;
typedef unsigned int   u32;
typedef __attribute__((ext_vector_type(4))) float floatx4;
typedef __attribute__((ext_vector_type(8))) short shortx8;

#define BB 8192
#define SS 18
#define DD 512

// ---------- helpers ----------
__device__ __forceinline__ u16 f2bf(float f){            // RNE f32->bf16
  u32 u = __float_as_uint(f);
  return (u16)((u + 0x7FFFu + ((u >> 16) & 1u)) >> 16);
}
__device__ __forceinline__ float bf2f(u16 x){ return __uint_as_float(((u32)x)<<16); }

__device__ __forceinline__ shortx8 pack8v(floatx4 a, floatx4 b){
  shortx8 t;
  t[0]=(short)f2bf(a[0]); t[1]=(short)f2bf(a[1]); t[2]=(short)f2bf(a[2]); t[3]=(short)f2bf(a[3]);
  t[4]=(short)f2bf(b[0]); t[5]=(short)f2bf(b[1]); t[6]=(short)f2bf(b[2]); t[7]=(short)f2bf(b[3]);
  return t;
}

__device__ __forceinline__ void gload16(const void* g, void* l){
  __builtin_amdgcn_global_load_lds((const __attribute__((address_space(1))) void*)g,
                                   (__attribute__((address_space(3))) void*)l, 16, 0, 0);
}

template<int CALLS>
__device__ __forceinline__ void gstage(const char* src, size_t rowStrideB, int chunkByteOff,
                                       char* lds, int wid, int lane){
#pragma unroll
  for (int i=0;i<CALLS;++i){
    int base = (wid*CALLS + i)*1024;
    int off  = base + lane*16;
    int row  = off >> 7;
    int blk  = ((off >> 4) & 7) ^ (row & 7);
    gload16(src + (size_t)row*rowStrideB + chunkByteOff + blk*16, lds + base);
  }
}

__device__ __forceinline__ void lds_store4(char* buf, int row, int rowBytes, int khByte,
                                           int swzMask, const shortx8* v){
#pragma unroll
  for (int q=0;q<4;++q){
    int off = row*rowBytes + khByte + q*16;
    off ^= (row & swzMask) << 4;
    *(shortx8*)(buf + off) = v[q];
  }
}

__device__ __forceinline__ void stage_bf16(char* buf, const u16* gsrc, size_t srcRowBytes, int tid){
  int row = tid >> 1, kh = tid & 1;
  const char* p = (const char*)gsrc + (size_t)row*srcRowBytes + kh*64;
  shortx8 v[4];
#pragma unroll
  for (int q=0;q<4;++q) v[q] = *(const shortx8*)(p + q*16);
  lds_store4(buf, row, 128, kh*64, 7, v);
}

__device__ __forceinline__ shortx8 lds_frag(const char* buf, int row, int rowBytes, int kByte,
                                            int swzMask, int lane){
  int off = row*rowBytes + kByte + ((lane>>4)<<4);
  off ^= (row & swzMask) << 4;
  return *(const shortx8*)(buf + off);
}

template<int MF, int NF>
__device__ __forceinline__ void mma64(const char* As, const char* Bs, int wm, int wn, int lane,
                                      floatx4 acc[MF][NF]){
#pragma unroll
  for (int kk=0; kk<2; ++kk){
    shortx8 a[MF], b[NF];
#pragma unroll
    for (int i=0;i<MF;++i) a[i] = lds_frag(As, wm + i*16 + (lane&15), 128, kk*64, 7, lane);
#pragma unroll
    for (int j=0;j<NF;++j) b[j] = lds_frag(Bs, wn + j*16 + (lane&15), 128, kk*64, 7, lane);
#pragma unroll
    for (int i=0;i<MF;++i)
#pragma unroll
      for (int j=0;j<NF;++j)
        acc[i][j] = __builtin_amdgcn_mfma_f32_16x16x32_bf16(a[i], b[j], acc[i][j], 0, 0, 0);
  }
}

// split: ds_read all frags, then MFMA on regs
template<int MF, int NF>
__device__ __forceinline__ void frags_load(const char* As, const char* Bs, int wm, int wn, int lane,
                                           shortx8 a[2][MF], shortx8 b[2][NF]){
#pragma unroll
  for (int kk=0;kk<2;++kk){
#pragma unroll
    for (int i=0;i<MF;++i) a[kk][i] = lds_frag(As, wm + i*16 + (lane&15), 128, kk*64, 7, lane);
#pragma unroll
    for (int j=0;j<NF;++j) b[kk][j] = lds_frag(Bs, wn + j*16 + (lane&15), 128, kk*64, 7, lane);
  }
}
template<int MF, int NF>
__device__ __forceinline__ void frags_mma(shortx8 a[2][MF], shortx8 b[2][NF], floatx4 acc[MF][NF]){
  __builtin_amdgcn_s_setprio(1);
#pragma unroll
  for (int kk=0;kk<2;++kk)
#pragma unroll
    for (int i=0;i<MF;++i)
#pragma unroll
      for (int j=0;j<NF;++j)
        acc[i][j] = __builtin_amdgcn_mfma_f32_16x16x32_bf16(a[kk][i], b[kk][j], acc[i][j], 0, 0, 0);
  __builtin_amdgcn_s_setprio(0);
}

// bijective XCD chunking (nwg % 8 == 0)
__device__ __forceinline__ int xcd_swz(int bid, int nwg){
  int q = nwg >> 3;
  return (bid & 7)*q + (bid >> 3);
}

// ---------- prep ----------
__global__ __launch_bounds__(256) void transpose_w2(const float* __restrict__ src,
                                                    u16* __restrict__ dst,
                                                    int sKstride, int kSrcOff, int Kuse,
                                                    int N, int Kpad, int kDstOff){
  __shared__ float tile[32][33];
  int s = blockIdx.z;
  int k0 = blockIdx.x*32, n0 = blockIdx.y*32;
  int tx = threadIdx.x & 31, ty = threadIdx.x >> 5;
#pragma unroll
  for (int r=0;r<4;++r){
    int k = k0 + ty*4 + r;
    float v = (k < Kuse) ? src[((size_t)s*sKstride + kSrcOff + k)*N + n0 + tx] : 0.f;
    tile[ty*4+r][tx] = v;
  }
  __syncthreads();
#pragma unroll
  for (int r=0;r<4;++r){
    int n = n0 + ty*4 + r;
    dst[((size_t)s*N + n)*Kpad + kDstOff + k0 + tx] = f2bf(tile[tx][ty*4+r]);
  }
}

// ---------- bn (unchanged): h2b + gsb side-write ----------
__global__ __launch_bounds__(256) void k_bn(const float* __restrict__ gs,
     const u16* __restrict__ w1t, const u16* __restrict__ w2t,
     const float* __restrict__ b1, const float* __restrict__ b2,
     u16* __restrict__ h2b, u16* __restrict__ gsb){
  __shared__ __align__(16) char SMB[40960];
  int tid = threadIdx.x, lane = tid & 63, wid = tid >> 6;
  int nb = xcd_swz(blockIdx.x, 1152);
  int m0 = (nb & 63)*128, s = nb >> 6;
  floatx4 acc[2][2] = {};
  const char*  Bsrc = (const char*)w1t + (size_t)s*32*1024;
  size_t rowIdx = ((size_t)(m0 + (tid>>1))*SS + s)*DD + (tid&1)*32;
  const float* Ags  = gs + rowIdx;
  u16*         Gsb  = gsb + rowIdx;
  floatx4 fr[8];
  gstage<1>(Bsrc, 1024, 0, SMB+32768, wid, lane);
#pragma unroll
  for (int q=0;q<8;++q) fr[q] = *(const floatx4*)(Ags + q*4);
  for (int c=0;c<8;++c){
    char* Asc = SMB + (c&1)*16384;
    char* Bsc = SMB + 32768 + (c&1)*4096;
    { shortx8 v[4];
#pragma unroll
      for (int q=0;q<4;++q) v[q] = pack8v(fr[2*q], fr[2*q+1]);
      u16* gp = Gsb + c*64;
#pragma unroll
      for (int q=0;q<4;++q) *(shortx8*)(gp + q*8) = v[q];
      lds_store4(Asc, tid>>1, 128, (tid&1)*64, 7, v); }
    __syncthreads();
    int cn = c+1;
    if (cn < 8){
      gstage<1>(Bsrc, 1024, cn*128, SMB + 32768 + (cn&1)*4096, wid, lane);
      const float* p = Ags + cn*64;
#pragma unroll
      for (int q=0;q<8;++q) fr[q] = *(const floatx4*)(p + q*4);
    }
    mma64<2,2>(Asc, Bsc, wid*32, 0, lane, acc);
  }
  __syncthreads();
  char* G1  = SMB;
  char* W2s = SMB + 8192;
#pragma unroll
  for (int i=0;i<2;++i)
#pragma unroll
   for (int j=0;j<2;++j){
    int col = j*16 + (lane&15);
    float bias = b1[s*32 + col];
#pragma unroll
    for (int r=0;r<4;++r){
      int row = wid*32 + i*16 + ((lane>>4)<<2) + r;
      float v = fmaxf(acc[i][j][r] + bias, 0.f);
      int off = (row*64 + col*2) ^ ((row&3)<<4);
      *(u16*)(G1 + off) = f2bf(v);
    }
  }
  if (tid < 32){
    const u16* p = w2t + (size_t)s*32*32 + tid*32;
#pragma unroll
    for (int q=0;q<4;++q){
      int off = (tid*64 + q*16) ^ ((tid&3)<<4);
      *(shortx8*)(W2s + off) = *(const shortx8*)(p + q*8);
    }
  }
  __syncthreads();
  floatx4 acc2[2][2] = {};
  {
    shortx8 a[2], b[2];
#pragma unroll
    for (int i=0;i<2;++i) a[i] = lds_frag(G1,  wid*32 + i*16 + (lane&15), 64, 0, 3, lane);
#pragma unroll
    for (int j=0;j<2;++j) b[j] = lds_frag(W2s, j*16 + (lane&15),          64, 0, 3, lane);
#pragma unroll
    for (int i=0;i<2;++i)
#pragma unroll
      for (int j=0;j<2;++j)
        acc2[i][j] = __builtin_amdgcn_mfma_f32_16x16x32_bf16(a[i], b[j], acc2[i][j], 0,0,0);
  }
#pragma unroll
  for (int i=0;i<2;++i)
#pragma unroll
   for (int j=0;j<2;++j){
    int col = j*16 + (lane&15);
    float bias = b2[s*32 + col];
#pragma unroll
    for (int r=0;r<4;++r){
      int row = wid*32 + i*16 + ((lane>>4)<<2) + r;
      h2b[((size_t)(m0+row)*SS + s)*32 + col] = f2bf(acc2[i][j][r] + bias);
    }
  }
}

// ---------- gm + age (unchanged) ----------
__global__ __launch_bounds__(256) void k_gm(const u16* __restrict__ h2b,
     const u16* __restrict__ w1t, const u16* __restrict__ w2t,
     const float* __restrict__ b1, const float* __restrict__ b2,
     const float* __restrict__ ta, const float* __restrict__ aw1, const float* __restrict__ ab1,
     const float* __restrict__ aw2, const float* __restrict__ ab2,
     u16* __restrict__ gfab){
  __shared__ __align__(16) char As[128*128];
  __shared__ __align__(16) char Bs[128*128];
  __shared__ __align__(16) char G1[128*256];
  int tid=threadIdx.x, lane=tid&63, w=tid>>6;
  int m0 = blockIdx.x*128;
  floatx4 acc[2][8] = {};
  for (int c=0;c<9;++c){
    __syncthreads();
    stage_bf16(As, h2b + (size_t)m0*576 + c*64, 1152, tid);
    stage_bf16(Bs, w1t + c*64,                 1152, tid);
    __syncthreads();
    mma64<2,8>(As, Bs, w*32, 0, lane, acc);
  }
#pragma unroll
  for (int i=0;i<2;++i)
#pragma unroll
   for (int j=0;j<8;++j){
    int col = j*16 + (lane&15);
    float bias = b1[col];
#pragma unroll
    for (int r=0;r<4;++r){
      int row = w*32 + i*16 + ((lane>>4)<<2) + r;
      float v = fmaxf(acc[i][j][r] + bias, 0.f);
      int off = (row*256 + col*2) ^ ((row&7)<<4);
      *(u16*)(G1 + off) = f2bf(v);
    }
  }
  floatx4 acc2[2][8] = {};
  for (int c2=0;c2<2;++c2){
    __syncthreads();
    stage_bf16(Bs, w2t + c2*64, 256, tid);
    __syncthreads();
#pragma unroll
    for (int kk=0;kk<2;++kk){
      shortx8 a[2], b[8];
#pragma unroll
      for (int i=0;i<2;++i){
        int row = w*32 + i*16 + (lane&15);
        int off = (row*256 + c2*128 + kk*64 + ((lane>>4)<<4)) ^ ((row&7)<<4);
        a[i] = *(const shortx8*)(G1 + off);
      }
#pragma unroll
      for (int j=0;j<8;++j) b[j] = lds_frag(Bs, j*16 + (lane&15), 128, kk*64, 7, lane);
#pragma unroll
      for (int i=0;i<2;++i)
#pragma unroll
        for (int j=0;j<8;++j)
          acc2[i][j] = __builtin_amdgcn_mfma_f32_16x16x32_bf16(a[i], b[j], acc2[i][j], 0,0,0);
    }
  }
#pragma unroll
  for (int i=0;i<2;++i)
#pragma unroll
   for (int j=0;j<8;++j){
    int col = j*16 + (lane&15);
    float bias = b2[col];
#pragma unroll
    for (int r=0;r<4;++r){
      int row = w*32 + i*16 + ((lane>>4)<<2) + r;
      gfab[(size_t)(m0+row)*192 + col] = f2bf(acc2[i][j][r] + bias);
    }
  }
  if (tid < 128){
    int bidx = m0 + tid;
    float t = ta[bidx];
    float a1[16];
#pragma unroll
    for (int j2=0;j2<16;++j2){ float v = t*aw1[j2] + ab1[j2]; a1[j2] = fmaxf(v, 0.f); }
#pragma unroll
    for (int m=0;m<16;++m){
      float v = ab2[m];
#pragma unroll
      for (int j2=0;j2<16;++j2) v += a1[j2]*aw2[j2*16+m];
      gfab[(size_t)bidx*192 + 128 + m] = f2bf(v);
    }
    shortx8 zz = {};
#pragma unroll
    for (int z=0;z<6;++z) *(shortx8*)(gfab + (size_t)bidx*192 + 144 + z*8) = zz;
  }
}

// ---------- fc1: 128x128 tile, 4 waves, 80KB LDS (2 blocks/CU), reg-queue A + 3-deep B ring ----------
__global__ __launch_bounds__(256, 2) void k_fc1(const u16* __restrict__ gfab,
     const u16* __restrict__ gsb, const u16* __restrict__ w1t,
     const float* __restrict__ b1, u16* __restrict__ y1b){
  __shared__ __align__(16) char SMB[81920];  // As 2x16KB @0, Bs 3x16KB @32768
  int tid=threadIdx.x, lane=tid&63, wid=tid>>6;
  int nb = xcd_swz(blockIdx.x, 4608);
  int n2 = nb&3, m0 = ((nb>>2)&63)*128, s = nb>>8;
  int wm = (wid>>1)*64, wn = (wid&1)*64;
  floatx4 acc[4][4] = {};
  // A: 2 thr/row, 64B each (4 x dwordx4)
  int ar = tid>>1, aq = (tid&1)*64;
  const char* pAg = (const char*)gfab + (size_t)(m0+ar)*384 + aq;
  const char* pAs = (const char*)gsb + ((size_t)(m0+ar)*SS + s)*1024 + aq;
  int wo0 = ar*128 + ((aq+ 0) ^ ((ar&7)<<4));
  int wo1 = ar*128 + ((aq+16) ^ ((ar&7)<<4));
  int wo2 = ar*128 + ((aq+32) ^ ((ar&7)<<4));
  int wo3 = ar*128 + ((aq+48) ^ ((ar&7)<<4));
  // B: 4 gload16/wave over 128 rows
  const char* gW = (const char*)w1t + ((size_t)s*512 + n2*128)*1408;
  const char* pB[4]; int ldB[4];
#pragma unroll
  for (int i=0;i<4;++i){
    int base=(wid*4+i)*1024, off=base+lane*16;
    int row=off>>7, blk=((off>>4)&7)^(row&7);
    pB[i] = gW + (size_t)row*1408 + blk*16;
    ldB[i] = base;
  }
  floatx4 qA0[4], qA1[4], qA2[4];
#define QS1(c) ((c)%3==0?qA0:((c)%3==1?qA1:qA2))
#define LDA1(c,Q) do{ if((c)<3){ \
      Q[0]=*(const floatx4*)(pAg+(c)*128);    Q[1]=*(const floatx4*)(pAg+(c)*128+16); \
      Q[2]=*(const floatx4*)(pAg+(c)*128+32); Q[3]=*(const floatx4*)(pAg+(c)*128+48); } \
    else { \
      Q[0]=*(const floatx4*)(pAs+((c)-3)*128);    Q[1]=*(const floatx4*)(pAs+((c)-3)*128+16); \
      Q[2]=*(const floatx4*)(pAs+((c)-3)*128+32); Q[3]=*(const floatx4*)(pAs+((c)-3)*128+48); } }while(0)
#define ISSB1(c) do{ char* _d=SMB+32768+((c)%3)*16384; \
    gload16(pB[0]+(c)*128,_d+ldB[0]); gload16(pB[1]+(c)*128,_d+ldB[1]); \
    gload16(pB[2]+(c)*128,_d+ldB[2]); gload16(pB[3]+(c)*128,_d+ldB[3]); }while(0)
  LDA1(0,qA0); __builtin_amdgcn_sched_barrier(0);
  ISSB1(0);    __builtin_amdgcn_sched_barrier(0);
  LDA1(1,qA1); __builtin_amdgcn_sched_barrier(0);
  ISSB1(1);    __builtin_amdgcn_sched_barrier(0);
  LDA1(2,qA2); __builtin_amdgcn_sched_barrier(0);
#pragma unroll
  for (int c=0;c<11;++c){
    if (c<9)       asm volatile("s_waitcnt vmcnt(12)" ::: "memory");
    else if (c==9) asm volatile("s_waitcnt vmcnt(8)" ::: "memory");
    else           asm volatile("s_waitcnt vmcnt(0)" ::: "memory");
    { char* As = SMB + (c&1)*16384;
      const floatx4* Q = QS1(c);
      *(floatx4*)(As+wo0) = Q[0]; *(floatx4*)(As+wo1) = Q[1];
      *(floatx4*)(As+wo2) = Q[2]; *(floatx4*)(As+wo3) = Q[3]; }
    asm volatile("s_waitcnt lgkmcnt(0)" ::: "memory");
    __builtin_amdgcn_s_barrier();
    shortx8 a[2][4], b[2][4];
    frags_load<4,4>(SMB + (c&1)*16384, SMB + 32768 + (c%3)*16384, wm, wn, lane, a, b);
    __builtin_amdgcn_sched_barrier(0);
    if (c+2<11) ISSB1(c+2);
    if (c+3<11) { LDA1(c+3, QS1(c+3)); }
    __builtin_amdgcn_sched_barrier(0);
    frags_mma<4,4>(a, b, acc);
  }
  __syncthreads();
  // epilogue: relu+bias -> SMB [128][256B] bf16 swizzled, then coalesced stores
#pragma unroll
  for (int i=0;i<4;++i)
#pragma unroll
   for (int j=0;j<4;++j){
    int col = wn + j*16 + (lane&15);
    float bias = b1[(size_t)s*512 + n2*128 + col];
#pragma unroll
    for (int r=0;r<4;++r){
      int row = wm + i*16 + ((lane>>4)<<2) + r;
      float v = fmaxf(acc[i][j][r] + bias, 0.f);
      int off = (row*256 + col*2) ^ ((row&7)<<4);
      *(u16*)(SMB + off) = f2bf(v);
    }
  }
  __syncthreads();
  {
    int row = tid>>1, half = tid&1;
    u16* gp = y1b + ((size_t)(m0+row)*SS + s)*DD + n2*128 + half*64;
#pragma unroll
    for (int q=0;q<8;++q){                    // FIX: q<8 (was q<4) — full 128B half-row
      int off = (row*256 + half*128 + q*16) ^ ((row&7)<<4);
      *(shortx8*)(gp + q*8) = *(const shortx8*)(SMB + off);
    }
  }
}

// ---------- fc2: 128x128 tile, 4 waves, 80KB LDS (2 blocks/CU); out = y1 @ w2 + b2 + gs ----------
__global__ __launch_bounds__(256, 2) void k_fc2(const u16* __restrict__ y1b,
     const u16* __restrict__ gsb, const u16* __restrict__ w2t,
     const float* __restrict__ b2, float* __restrict__ out){
  __shared__ __align__(16) char SMB[81920];  // As 2x16KB @0, Bs 3x16KB @32768
  int tid=threadIdx.x, lane=tid&63, wid=tid>>6;
  int nb = xcd_swz(blockIdx.x, 4608);
  int n2 = nb&3, m0 = ((nb>>2)&63)*128, s = nb>>8;
  int wm = (wid>>1)*64, wn = (wid&1)*64;
  floatx4 acc[4][4] = {};
  int ar = tid>>1, aq = (tid&1)*64;
  const char* pA = (const char*)y1b + ((size_t)(m0+ar)*SS + s)*1024 + aq;
  int wo0 = ar*128 + ((aq+ 0) ^ ((ar&7)<<4));
  int wo1 = ar*128 + ((aq+16) ^ ((ar&7)<<4));
  int wo2 = ar*128 + ((aq+32) ^ ((ar&7)<<4));
  int wo3 = ar*128 + ((aq+48) ^ ((ar&7)<<4));
  const char* gW = (const char*)w2t + ((size_t)s*512 + n2*128)*1024;
  const char* pB[4]; int ldB[4];
#pragma unroll
  for (int i=0;i<4;++i){
    int base=(wid*4+i)*1024, off=base+lane*16;
    int row=off>>7, blk=((off>>4)&7)^(row&7);
    pB[i] = gW + (size_t)row*1024 + blk*16;
    ldB[i] = base;
  }
  floatx4 qA0[4], qA1[4], qA2[4];
#define QS2(c) ((c)%3==0?qA0:((c)%3==1?qA1:qA2))
#define LDA2(c,Q) do{ \
    Q[0]=*(const floatx4*)(pA+(c)*128);    Q[1]=*(const floatx4*)(pA+(c)*128+16); \
    Q[2]=*(const floatx4*)(pA+(c)*128+32); Q[3]=*(const floatx4*)(pA+(c)*128+48); }while(0)
#define ISSB2(c) do{ char* _d=SMB+32768+((c)%3)*16384; \
    gload16(pB[0]+(c)*128,_d+ldB[0]); gload16(pB[1]+(c)*128,_d+ldB[1]); \
    gload16(pB[2]+(c)*128,_d+ldB[2]); gload16(pB[3]+(c)*128,_d+ldB[3]); }while(0)
  LDA2(0,qA0); __builtin_amdgcn_sched_barrier(0);
  ISSB2(0);    __builtin_amdgcn_sched_barrier(0);
  LDA2(1,qA1); __builtin_amdgcn_sched_barrier(0);
  ISSB2(1);    __builtin_amdgcn_sched_barrier(0);
  LDA2(2,qA2); __builtin_amdgcn_sched_barrier(0);
#pragma unroll
  for (int c=0;c<8;++c){
    if (c<6)       asm volatile("s_waitcnt vmcnt(12)" ::: "memory");
    else if (c==6) asm volatile("s_waitcnt vmcnt(8)" ::: "memory");
    else           asm volatile("s_waitcnt vmcnt(0)" ::: "memory");
    { char* As = SMB + (c&1)*16384;
      const floatx4* Q = QS2(c);
      *(floatx4*)(As+wo0) = Q[0]; *(floatx4*)(As+wo1) = Q[1];
      *(floatx4*)(As+wo2) = Q[2]; *(floatx4*)(As+wo3) = Q[3]; }
    asm volatile("s_waitcnt lgkmcnt(0)" ::: "memory");
    __builtin_amdgcn_s_barrier();
    shortx8 a[2][4], b[2][4];
    frags_load<4,4>(SMB + (c&1)*16384, SMB + 32768 + (c%3)*16384, wm, wn, lane, a, b);
    __builtin_amdgcn_sched_barrier(0);
    if (c+2<8) ISSB2(c+2);
    if (c+3<8) { LDA2(c+3, QS2(c+3)); }
    __builtin_amdgcn_sched_barrier(0);
    frags_mma<4,4>(a, b, acc);
  }
  __syncthreads();
  // epilogue single-phase: fp32 LDS [128][512B] (64KB), then coalesced out-stores
  float* SMF = (float*)SMB;
#pragma unroll
  for (int i=0;i<4;++i)
#pragma unroll
   for (int j=0;j<4;++j){
    int col = wn + j*16 + (lane&15);
#pragma unroll
    for (int r=0;r<4;++r){
      int row = wm + i*16 + ((lane>>4)<<2) + r;
      int off = (row*512 + col*4) ^ ((row&7)<<4);
      *(float*)((char*)SMF + off) = acc[i][j][r];
    }
  }
  __syncthreads();
  {
    int row = tid>>1, half = tid&1;
    size_t gidx = ((size_t)(m0+row)*SS + s)*DD + n2*128 + half*64;
    const float* bp = b2 + (size_t)s*512 + n2*128 + half*64;
    const u16*   gp = gsb + gidx;
    shortx8 gv[8];
#pragma unroll
    for (int q=0;q<8;++q) gv[q] = *(const shortx8*)(gp + q*8);
#pragma unroll
    for (int q=0;q<16;++q){
      int off = (row*512 + half*256 + q*16) ^ ((row&7)<<4);
      floatx4 v = *(const floatx4*)((char*)SMF + off);
      floatx4 bb = *(const floatx4*)(bp + q*4);
      floatx4 g;
      g[0]=bf2f((u16)gv[q>>1][(q&1)*4+0]); g[1]=bf2f((u16)gv[q>>1][(q&1)*4+1]);
      g[2]=bf2f((u16)gv[q>>1][(q&1)*4+2]); g[3]=bf2f((u16)gv[q>>1][(q&1)*4+3]);
      *(floatx4*)(out + gidx + q*4) = v + bb + g;
    }
  }
}

// ---------- launch ----------
extern "C" void kernel_launch(void* const* d_in, const int* in_sizes, int n_in,
                              void* d_out, int out_size, void* d_ws, size_t ws_size,
                              hipStream_t stream){
  (void)in_sizes; (void)n_in; (void)out_size; (void)ws_size;
  const float* gs   = (const float*)d_in[1];
  const float* ta   = (const float*)d_in[2];
  const float* bnw1 = (const float*)d_in[3];
  const float* bnb1 = (const float*)d_in[4];
  const float* bnw2 = (const float*)d_in[5];
  const float* bnb2 = (const float*)d_in[6];
  const float* gmw1 = (const float*)d_in[7];
  const float* gmb1 = (const float*)d_in[8];
  const float* gmw2 = (const float*)d_in[9];
  const float* gmb2 = (const float*)d_in[10];
  const float* aw1  = (const float*)d_in[11];
  const float* ab1  = (const float*)d_in[12];
  const float* aw2  = (const float*)d_in[13];
  const float* ab2  = (const float*)d_in[14];
  const float* fcw1 = (const float*)d_in[15];
  const float* fcb1 = (const float*)d_in[16];
  const float* fcw2 = (const float*)d_in[17];
  const float* fcb2 = (const float*)d_in[18];

  char* ws = (char*)d_ws;
  u16* fcW1t = (u16*)(ws + 0);                  // 12,976,128
  u16* fcW2t = (u16*)(ws + 12976128);           //  9,437,184
  u16* bnW1t = (u16*)(ws + 22413312);           //    589,824
  u16* bnW2t = (u16*)(ws + 23003136);           //     36,864
  u16* gmW1t = (u16*)(ws + 23040000);           //    147,456
  u16* gmW2t = (u16*)(ws + 23187456);           //     32,768
  u16* h2b   = (u16*)(ws + 23220224);           //  9,437,184
  u16* gfab  = (u16*)(ws + 32657408);           //  3,145,728 (B x 192)
  u16* y1b   = (u16*)(ws + 35803136);           // 150,994,944
  u16* gsb   = (u16*)(ws + 186798080);          // 150,994,944 (end 337,793,024)
  float* out = (float*)d_out;

  dim3 blk(256);
  transpose_w2<<<dim3(16,1,18),  blk, 0, stream>>>(bnw1, bnW1t, 512, 0, 512,  32, 512, 0);
  transpose_w2<<<dim3(1,1,18),   blk, 0, stream>>>(bnw2, bnW2t,  32, 0,  32,  32,  32, 0);
  transpose_w2<<<dim3(18,4,1),   blk, 0, stream>>>(gmw1, gmW1t, 576, 0, 576, 128, 576, 0);
  transpose_w2<<<dim3(4,4,1),    blk, 0, stream>>>(gmw2, gmW2t, 128, 0, 128, 128, 128, 0);
  transpose_w2<<<dim3(6,16,18),  blk, 0, stream>>>(fcw1, fcW1t, 656, 0,   144, 512, 704, 0);
  transpose_w2<<<dim3(16,16,18), blk, 0, stream>>>(fcw1, fcW1t, 656, 144, 512, 512, 704, 192);
  transpose_w2<<<dim3(16,16,18), blk, 0, stream>>>(fcw2, fcW2t, 512, 0, 512, 512, 512, 0);

  k_bn <<<dim3(1152), blk, 0, stream>>>(gs, bnW1t, bnW2t, bnb1, bnb2, h2b, gsb);
  k_gm <<<dim3(64),   blk, 0, stream>>>(h2b, gmW1t, gmW2t, gmb1, gmb2, ta, aw1, ab1, aw2, ab2, gfab);
  k_fc1<<<dim3(4608), blk, 0, stream>>>(gfab, gsb, fcW1t, fcb1, y1b);
  k_fc2<<<dim3(4608), blk, 0, stream>>>(y1b, gsb, fcW2t, fcb2, out);
}